// Round 1
// baseline (1609.488 us; speedup 1.0000x reference)
//
#include <hip/hip_runtime.h>
#include <math.h>

typedef __attribute__((ext_vector_type(8))) short short8;
typedef __attribute__((ext_vector_type(4))) float f32x4;

typedef const __attribute__((address_space(1))) void gv_t;
typedef __attribute__((address_space(3))) void lv_t;

__device__ __forceinline__ float b2f(short u) {
  union { unsigned int i; float f; } c; c.i = ((unsigned int)(unsigned short)u) << 16; return c.f;
}
__device__ __forceinline__ short f2b(float f) {
  union { float f; unsigned int i; } c; c.f = f;
  unsigned int r = c.i + 0x7FFFu + ((c.i >> 16) & 1u);
  return (short)(r >> 16);
}

// ---------------- prep kernels ----------------

__global__ __launch_bounds__(256) void k_convA(const float* __restrict__ in, short* __restrict__ out, int n8) {
  int idx = blockIdx.x * 256 + threadIdx.x;
  if (idx >= n8) return;
  const float4* p = (const float4*)(in + (size_t)idx * 8);
  float4 a = p[0], b = p[1];
  short8 r;
  r[0]=f2b(a.x); r[1]=f2b(a.y); r[2]=f2b(a.z); r[3]=f2b(a.w);
  r[4]=f2b(b.x); r[5]=f2b(b.y); r[6]=f2b(b.z); r[7]=f2b(b.w);
  *(short8*)(out + (size_t)idx*8) = r;
}

__global__ __launch_bounds__(256) void k_transpose_bf(const float* __restrict__ in, short* __restrict__ out, int K, int N) {
  size_t idx = (size_t)blockIdx.x * 256 + threadIdx.x;
  if (idx >= (size_t)K * N) return;
  int kk = (int)(idx / N), n = (int)(idx % N);
  out[(size_t)n * K + kk] = f2b(in[idx]);
}

__global__ __launch_bounds__(256) void k_prep_kv(const float* __restrict__ wk, const float* __restrict__ wv, short* __restrict__ out) {
  int i = blockIdx.x * 256 + threadIdx.x;
  if (i >= 524288) return;
  int kk = i >> 10, n = i & 1023;
  float v = (n < 512) ? wk[kk*512 + n] : wv[kk*512 + (n - 512)];
  out[(size_t)n * 512 + kk] = f2b(v);
}

__global__ __launch_bounds__(256) void k_slots_init(const float* __restrict__ mu, const float* __restrict__ lsig,
                                                    const float* __restrict__ noise, float* __restrict__ slots) {
  int idx = blockIdx.x * 256 + threadIdx.x; // 196608 total
  int sd = idx % 6144;
  slots[idx] = mu[sd] + __expf(lsig[sd]) * noise[idx];
}

// ---------------- bf16 MFMA GEMM: C = A(MxK) @ Bt(NxK)^T + bias, bf16 out ----------------
// 128x128 tile, BK=32, 256 threads (4 waves, 2x2 wave grid, 64x64 per wave)

__global__ __launch_bounds__(256) void gemm_bt(
    const short* __restrict__ A, const short* __restrict__ Bt,
    const float* __restrict__ bias, short* __restrict__ C,
    int M, int N, int K)
{
  __shared__ short As[128*32];
  __shared__ short Bs[128*32];
  const int t = threadIdx.x;
  const int lane = t & 63, wave = t >> 6;
  const int rowBase = blockIdx.y * 128, colBase = blockIdx.x * 128;
  const int wm = (wave >> 1) * 64, wn = (wave & 1) * 64;
  const int fr = lane & 15, fk = (lane >> 4) * 8;
  f32x4 acc[4][4] = {};
  const int c0 = t, c1 = 256 + t;
  const int r0 = c0 >> 2, k0 = (c0 & 3) * 8;
  const int r1 = c1 >> 2, k1 = (c1 & 3) * 8;
  for (int kb = 0; kb < K; kb += 32) {
    __syncthreads();
    __builtin_amdgcn_global_load_lds((gv_t*)(A + (size_t)(rowBase + r0)*K + kb + k0), (lv_t*)(As + c0*8), 16, 0, 0);
    __builtin_amdgcn_global_load_lds((gv_t*)(A + (size_t)(rowBase + r1)*K + kb + k1), (lv_t*)(As + c1*8), 16, 0, 0);
    __builtin_amdgcn_global_load_lds((gv_t*)(Bt + (size_t)(colBase + r0)*K + kb + k0), (lv_t*)(Bs + c0*8), 16, 0, 0);
    __builtin_amdgcn_global_load_lds((gv_t*)(Bt + (size_t)(colBase + r1)*K + kb + k1), (lv_t*)(Bs + c1*8), 16, 0, 0);
    __syncthreads();
    short8 af[4], bf[4];
    #pragma unroll
    for (int m = 0; m < 4; ++m) af[m] = *(const short8*)(As + (wm + m*16 + fr)*32 + fk);
    #pragma unroll
    for (int n = 0; n < 4; ++n) bf[n] = *(const short8*)(Bs + (wn + n*16 + fr)*32 + fk);
    #pragma unroll
    for (int m = 0; m < 4; ++m)
      #pragma unroll
      for (int n = 0; n < 4; ++n)
        acc[m][n] = __builtin_amdgcn_mfma_f32_16x16x32_bf16(af[m], bf[n], acc[m][n], 0, 0, 0);
  }
  const int cr = (lane >> 4) * 4, cc = lane & 15;
  #pragma unroll
  for (int m = 0; m < 4; ++m) {
    #pragma unroll
    for (int n = 0; n < 4; ++n) {
      int col = colBase + wn + n*16 + cc;
      float bv = bias ? bias[col] : 0.f;
      #pragma unroll
      for (int j = 0; j < 4; ++j) {
        int row = rowBase + wm + m*16 + cr + j;
        C[(size_t)row * N + col] = f2b(acc[m][n][j] + bv);
      }
    }
  }
}

// ---------------- double layernorm: inp = LN2(LN1(y)) , bf16 in/out, wave per row ----------------

__global__ __launch_bounds__(256) void k_ln2(const short* __restrict__ y, short* __restrict__ inp,
    const float* __restrict__ g1, const float* __restrict__ b1,
    const float* __restrict__ g2, const float* __restrict__ b2)
{
  int t = threadIdx.x, lane = t & 63;
  int row = blockIdx.x * 4 + (t >> 6);
  const short8 raw = *(const short8*)(y + (size_t)row*512 + lane*8);
  float x[8];
  #pragma unroll
  for (int e = 0; e < 8; ++e) x[e] = b2f(raw[e]);
  float s = 0.f, ss = 0.f;
  #pragma unroll
  for (int e = 0; e < 8; ++e) { s += x[e]; ss += x[e]*x[e]; }
  #pragma unroll
  for (int m = 1; m < 64; m <<= 1) { s += __shfl_xor(s, m, 64); ss += __shfl_xor(ss, m, 64); }
  float mean = s * (1.f/512.f);
  float rs = rsqrtf(ss*(1.f/512.f) - mean*mean + 1e-5f);
  int c = lane * 8;
  #pragma unroll
  for (int e = 0; e < 8; ++e) x[e] = (x[e]-mean)*rs*g1[c+e] + b1[c+e];
  s = 0.f; ss = 0.f;
  #pragma unroll
  for (int e = 0; e < 8; ++e) { s += x[e]; ss += x[e]*x[e]; }
  #pragma unroll
  for (int m = 1; m < 64; m <<= 1) { s += __shfl_xor(s, m, 64); ss += __shfl_xor(ss, m, 64); }
  float mean2 = s * (1.f/512.f);
  float rs2 = rsqrtf(ss*(1.f/512.f) - mean2*mean2 + 1e-5f);
  short8 o;
  #pragma unroll
  for (int e = 0; e < 8; ++e) o[e] = f2b((x[e]-mean2)*rs2*g2[c+e] + b2[c+e]);
  *(short8*)(inp + (size_t)row*512 + lane*8) = o;
}

// ---------------- single layernorm fp32 -> fp32, wave per row (512 cols) ----------------

__global__ __launch_bounds__(256) void k_ln1(const float* __restrict__ x, float* __restrict__ out,
    const float* __restrict__ g, const float* __restrict__ b)
{
  int t = threadIdx.x, lane = t & 63;
  int row = blockIdx.x * 4 + (t >> 6);
  const float* src = x + (size_t)row*512 + lane*8;
  float v[8];
  *(float4*)v = *(const float4*)src;
  *(float4*)(v+4) = *(const float4*)(src+4);
  float s = 0.f, ss = 0.f;
  #pragma unroll
  for (int e = 0; e < 8; ++e) { s += v[e]; ss += v[e]*v[e]; }
  #pragma unroll
  for (int m = 1; m < 64; m <<= 1) { s += __shfl_xor(s, m, 64); ss += __shfl_xor(ss, m, 64); }
  float mean = s * (1.f/512.f);
  float rs = rsqrtf(ss*(1.f/512.f) - mean*mean + 1e-5f);
  int c = lane * 8;
  float o[8];
  #pragma unroll
  for (int e = 0; e < 8; ++e) o[e] = (v[e]-mean)*rs*g[c+e] + b[c+e];
  float* dst = out + (size_t)row*512 + c;
  *(float4*)dst = *(float4*)o;
  *(float4*)(dst+4) = *(float4*)(o+4);
}

// ---------------- generic fp32 sgemm: C = act(A@B + bias) (+ add), 64x128 tile ----------------

__global__ __launch_bounds__(256) void sgemm(
    const float* __restrict__ A, const float* __restrict__ B,
    const float* __restrict__ bias, const float* __restrict__ add,
    float* __restrict__ C, int M, int N, int K, int act)
{
  __shared__ __align__(16) float As[32][68];
  __shared__ __align__(16) float Bs[32][132];
  int t = threadIdx.x;
  int bm = blockIdx.y * 64, bn = blockIdx.x * 128;
  int tm = (t >> 4) * 4, tn = (t & 15) * 8;
  float acc[4][8] = {};
  for (int kb = 0; kb < K; kb += 32) {
    __syncthreads();
    #pragma unroll
    for (int i = 0; i < 2; ++i) {
      int c = i*256 + t;
      int m = c >> 3, k4 = (c & 7) * 4;
      float4 v = *(const float4*)(A + (size_t)(bm+m)*K + kb + k4);
      As[k4+0][m] = v.x; As[k4+1][m] = v.y; As[k4+2][m] = v.z; As[k4+3][m] = v.w;
    }
    #pragma unroll
    for (int i = 0; i < 4; ++i) {
      int c = i*256 + t;
      int k = c >> 5, n4 = (c & 31) * 4;
      *(float4*)&Bs[k][n4] = *(const float4*)(B + (size_t)(kb+k)*N + bn + n4);
    }
    __syncthreads();
    #pragma unroll
    for (int kk = 0; kk < 32; ++kk) {
      float a[4], bb[8];
      *(float4*)a = *(const float4*)&As[kk][tm];
      *(float4*)bb = *(const float4*)&Bs[kk][tn];
      *(float4*)(bb+4) = *(const float4*)&Bs[kk][tn+4];
      #pragma unroll
      for (int m = 0; m < 4; ++m)
        #pragma unroll
        for (int n = 0; n < 8; ++n)
          acc[m][n] += a[m] * bb[n];
    }
  }
  #pragma unroll
  for (int m = 0; m < 4; ++m) {
    int row = bm + tm + m;
    #pragma unroll
    for (int n = 0; n < 8; ++n) {
      int col = bn + tn + n;
      float v = acc[m][n] + (bias ? bias[col] : 0.f);
      if (act == 1) v = 0.5f*v*(1.f + erff(v*0.70710678118f));
      else if (act == 2) v = fmaxf(v, 0.f);
      if (add) v += add[(size_t)row*N + col];
      C[(size_t)row*N + col] = v;
    }
  }
}

// ---------------- attention: dots = q . k * SCALE ----------------
// grid (jt=8, h=8, b=32); dots layout [b][j][s*8+h]

__global__ __launch_bounds__(256) void k_dots(const float* __restrict__ q, const short* __restrict__ kv,
                                              float* __restrict__ dots)
{
  __shared__ __align__(16) float qs[12][64];
  __shared__ float ks[128][65];
  int t = threadIdx.x;
  int jt = blockIdx.x, h = blockIdx.y, b = blockIdx.z;
  if (t < 192) {
    int s = t >> 4, d4 = (t & 15) * 4;
    *(float4*)&qs[s][d4] = *(const float4*)(q + (size_t)(b*12+s)*512 + h*64 + d4);
  }
  #pragma unroll
  for (int i = 0; i < 4; ++i) {
    int c = i*256 + t;
    int jj = c >> 3, seg = (c & 7) * 8;
    short8 raw = *(const short8*)(kv + ((size_t)(b*1024 + jt*128 + jj))*1024 + h*64 + seg);
    #pragma unroll
    for (int e = 0; e < 8; ++e) ks[jj][seg+e] = b2f(raw[e]);
  }
  __syncthreads();
  int jj = t & 127, sg = t >> 7;
  float d6[6] = {};
  for (int d = 0; d < 64; ++d) {
    float kvv = ks[jj][d];
    #pragma unroll
    for (int i = 0; i < 6; ++i) d6[i] += qs[sg*6+i][d] * kvv;
  }
  float* o = dots + ((size_t)(b*1024 + jt*128 + jj))*96 + h;
  #pragma unroll
  for (int i = 0; i < 6; ++i) o[(sg*6+i)*8] = d6[i] * 0.125f;
}

// ---------------- softmax over the 96 (s,h) axis, in place; optional attn_out ----------------

__global__ __launch_bounds__(256) void k_soft(float* __restrict__ dots, float* __restrict__ aout)
{
  int t = threadIdx.x, b = blockIdx.y;
  int j = blockIdx.x * 256 + t;
  float* p = dots + ((size_t)(b*1024 + j)) * 96;
  float v[96];
  #pragma unroll
  for (int i = 0; i < 24; ++i) *(float4*)&v[i*4] = *(const float4*)(p + i*4);
  float mx = v[0];
  #pragma unroll
  for (int i = 1; i < 96; ++i) mx = fmaxf(mx, v[i]);
  float sum = 0.f;
  #pragma unroll
  for (int i = 0; i < 96; ++i) { v[i] = __expf(v[i]-mx); sum += v[i]; }
  float inv = 1.f/sum;
  #pragma unroll
  for (int i = 0; i < 96; ++i) v[i] *= inv;
  #pragma unroll
  for (int i = 0; i < 24; ++i) *(float4*)(p + i*4) = *(float4*)&v[i*4];
  if (aout) {
    #pragma unroll
    for (int s = 0; s < 8; ++s) {
      float m = 0.f;
      #pragma unroll
      for (int hh = 0; hh < 8; ++hh) m += v[s*8+hh];
      aout[(size_t)(b*8+s)*1024 + j] = m * 0.125f;
    }
  }
}

// ---------------- vsum[b][h*64+d] = sum_j v ----------------

__global__ __launch_bounds__(256) void k_vsum(const short* __restrict__ kv, float* __restrict__ vsum)
{
  __shared__ float part[128];
  int t = threadIdx.x;
  int cq = blockIdx.x, b = blockIdx.y;
  int c = cq*128 + (t & 127), jh = t >> 7;
  float acc = 0.f;
  for (int j = jh*512; j < jh*512 + 512; ++j)
    acc += b2f(kv[((size_t)(b*1024 + j))*1024 + 512 + c]);
  if (jh == 1) part[t & 127] = acc;
  __syncthreads();
  if (jh == 0) vsum[b*512 + c] = acc + part[t & 127];
}

// ---------------- upd = (sum_j v*attn + 1e-8*vsum) / (den + 1e-8) ; grid (h=8, b=32) ----------------

__global__ __launch_bounds__(256) void k_upd(const float* __restrict__ dots, const short* __restrict__ kv,
    const float* __restrict__ vsum, float* __restrict__ upd)
{
  __shared__ float atts[12][129];
  __shared__ float vs[128][65];
  __shared__ float den_s[12];
  int t = threadIdx.x;
  int h = blockIdx.x, b = blockIdx.y;
  int d = t & 63, sq = t >> 6;
  int jj2 = t & 127, sg = t >> 7;
  float acc[3] = {0.f, 0.f, 0.f};
  float myden = 0.f;
  for (int jt = 0; jt < 8; ++jt) {
    __syncthreads();
    const float* src = dots + ((size_t)(b*1024 + jt*128 + jj2))*96 + h;
    #pragma unroll
    for (int i = 0; i < 6; ++i) atts[sg*6+i][jj2] = src[(sg*6+i)*8];
    #pragma unroll
    for (int i = 0; i < 4; ++i) {
      int c = i*256 + t;
      int jj = c >> 3, seg = (c & 7)*8;
      short8 raw = *(const short8*)(kv + ((size_t)(b*1024 + jt*128 + jj))*1024 + 512 + h*64 + seg);
      #pragma unroll
      for (int e = 0; e < 8; ++e) vs[jj][seg+e] = b2f(raw[e]);
    }
    __syncthreads();
    for (int jj = 0; jj < 128; ++jj) {
      float vv = vs[jj][d];
      #pragma unroll
      for (int i = 0; i < 3; ++i) acc[i] += atts[sq + 4*i][jj] * vv;
    }
    if (t < 12) {
      float ls = 0.f;
      for (int jj = 0; jj < 128; ++jj) ls += atts[t][jj];
      myden += ls;
    }
  }
  __syncthreads();
  if (t < 12) den_s[t] = myden;
  __syncthreads();
  #pragma unroll
  for (int i = 0; i < 3; ++i) {
    int s = sq + 4*i;
    int col = h*64 + d;
    float r = (acc[i] + 1e-8f * vsum[b*512 + col]) / (den_s[s] + 1e-8f);
    upd[(size_t)(b*12+s)*512 + col] = r;
  }
}

// ---------------- GRU gate combine (reads gx, gh; updates slots in place) ----------------

__global__ __launch_bounds__(256) void k_gruact(const float* __restrict__ gx, const float* __restrict__ gh,
                                                float* __restrict__ slots)
{
  int idx = blockIdx.x*256 + threadIdx.x; // 196608
  int row = idx >> 9, c = idx & 511;
  const float* gxr = gx + (size_t)row*1536;
  const float* ghr = gh + (size_t)row*1536;
  float r = 1.f/(1.f + __expf(-(gxr[c] + ghr[c])));
  float z = 1.f/(1.f + __expf(-(gxr[512+c] + ghr[512+c])));
  float n = tanhf(gxr[1024+c] + r*ghr[1024+c]);
  float h = slots[idx];
  slots[idx] = (1.f - z)*n + z*h;
}

// ---------------- selector head: logits, decision logic, obj write ----------------

__global__ __launch_bounds__(64) void k_decide(const float* __restrict__ hid, const float* __restrict__ w2,
    const float* __restrict__ b2, const float* __restrict__ slots, float* __restrict__ out)
{
  __shared__ float lg[16];
  __shared__ float dec[8];
  int b = blockIdx.x, t = threadIdx.x;
  if (t < 16) {
    int s = t >> 1, cl = t & 1;
    const float* hr = hid + (size_t)(b*12+s)*256;
    float a = b2[cl];
    for (int k = 0; k < 256; ++k) a += hr[k] * w2[k*2+cl];
    lg[t] = a;
  }
  __syncthreads();
  if (t == 0) {
    float d0[8]; float tot = 0.f;
    #pragma unroll
    for (int s = 0; s < 8; ++s) { d0[s] = (lg[2*s+1] > lg[2*s]) ? 1.f : 0.f; tot += d0[s]; }
    float needed = fmaxf(0.f, 2.f - tot);
    float cum = 0.f;
    #pragma unroll
    for (int s = 0; s < 8; ++s) {
      cum += 1.f - d0[s];
      float add = (d0[s] == 0.f && cum <= needed) ? 1.f : 0.f;
      float dd = d0[s] + add;
      dec[s] = dd;
      out[131072 + b*8 + s] = dd;
    }
  }
  __syncthreads();
  for (int i = 0; i < 64; ++i) {
    int idx = i*64 + t;
    int s = idx >> 9, c = idx & 511;
    out[(size_t)(b*8+s)*512 + c] = slots[(size_t)(b*12+s)*512 + c] * dec[s];
  }
}

// ---------------- host ----------------

extern "C" void kernel_launch(void* const* d_in, const int* in_sizes, int n_in,
                              void* d_out, int out_size, void* d_ws, size_t ws_size,
                              hipStream_t stream) {
  const float* features = (const float*)d_in[0];
  const float* noise    = (const float*)d_in[1];
  const float* w_in     = (const float*)d_in[2];
  const float* b_in     = (const float*)d_in[3];
  const float* ln1_g    = (const float*)d_in[4];
  const float* ln1_b    = (const float*)d_in[5];
  const float* slot_mu  = (const float*)d_in[6];
  const float* slot_ls  = (const float*)d_in[7];
  const float* wq       = (const float*)d_in[8];
  const float* wk       = (const float*)d_in[9];
  const float* wv       = (const float*)d_in[10];
  const float* gru_wih  = (const float*)d_in[11];
  const float* gru_whh  = (const float*)d_in[12];
  const float* gru_bih  = (const float*)d_in[13];
  const float* gru_bhh  = (const float*)d_in[14];
  const float* nslots_g = (const float*)d_in[15];
  const float* nslots_b = (const float*)d_in[16];
  const float* ninput_g = (const float*)d_in[17];
  const float* ninput_b = (const float*)d_in[18];
  const float* ffnln_g  = (const float*)d_in[19];
  const float* ffnln_b  = (const float*)d_in[20];
  const float* ffn_w1   = (const float*)d_in[21];
  const float* ffn_b1   = (const float*)d_in[22];
  const float* ffn_w2   = (const float*)d_in[23];
  const float* ffn_b2   = (const float*)d_in[24];
  const float* sel_w1   = (const float*)d_in[25];
  const float* sel_b1   = (const float*)d_in[26];
  const float* sel_w2   = (const float*)d_in[27];
  const float* sel_b2   = (const float*)d_in[28];
  float* out = (float*)d_out;
  const float* fnull = (const float*)nullptr;

  char* w = (char*)d_ws;
  size_t off = 0;
  auto alloc = [&](size_t n) { char* p = w + off; off = (off + n + 255) & ~255ULL; return p; };
  short* Abf  = (short*)alloc(75497472);   // features bf16 (32768x1152); later reused as kv
  short* kv   = Abf;                       // (32768x1024) bf16, written after Abf is dead
  short* ybf  = (short*)alloc(33554432);   // gemm1 out bf16; later reused as dots
  float* dots = (float*)ybf;               // (32*1024*96) fp32 = 12.6MB
  short* inp  = (short*)alloc(33554432);   // LN'd input bf16
  short* Bt1  = (short*)alloc(1179648);    // w_in^T bf16 (512x1152)
  short* Btkv = (short*)alloc(1048576);    // [wk|wv]^T bf16 (1024x512)
  float* slots= (float*)alloc(786432);
  float* sn   = (float*)alloc(786432);
  float* qb   = (float*)alloc(786432);
  float* upd  = (float*)alloc(786432);
  float* gx   = (float*)alloc(2359296);
  float* gh   = (float*)alloc(2359296);
  float* fln  = (float*)alloc(786432);
  float* f1   = (float*)alloc(3145728);
  float* hid  = (float*)alloc(393216);
  float* vsum = (float*)alloc(65536);
  (void)ws_size; (void)in_sizes; (void)n_in; (void)out_size;

  k_convA<<<dim3(18432), dim3(256), 0, stream>>>(features, Abf, 4718592);
  k_transpose_bf<<<dim3(2304), dim3(256), 0, stream>>>(w_in, Bt1, 1152, 512);
  k_prep_kv<<<dim3(2048), dim3(256), 0, stream>>>(wk, wv, Btkv);
  k_slots_init<<<dim3(768), dim3(256), 0, stream>>>(slot_mu, slot_ls, noise, slots);

  gemm_bt<<<dim3(4, 256), dim3(256), 0, stream>>>(Abf, Bt1, b_in, ybf, 32768, 512, 1152);
  k_ln2<<<dim3(8192), dim3(256), 0, stream>>>(ybf, inp, ln1_g, ln1_b, ninput_g, ninput_b);
  gemm_bt<<<dim3(8, 256), dim3(256), 0, stream>>>(inp, Btkv, fnull, kv, 32768, 1024, 512);
  k_vsum<<<dim3(4, 32), dim3(256), 0, stream>>>(kv, vsum);

  for (int it = 0; it < 3; ++it) {
    k_ln1<<<dim3(96), dim3(256), 0, stream>>>(slots, sn, nslots_g, nslots_b);
    sgemm<<<dim3(4, 6), dim3(256), 0, stream>>>(sn, wq, fnull, fnull, qb, 384, 512, 512, 0);
    k_dots<<<dim3(8, 8, 32), dim3(256), 0, stream>>>(qb, kv, dots);
    k_soft<<<dim3(4, 32), dim3(256), 0, stream>>>(dots, it == 2 ? out + 131328 : (float*)nullptr);
    k_upd<<<dim3(8, 32), dim3(256), 0, stream>>>(dots, kv, vsum, upd);
    sgemm<<<dim3(12, 6), dim3(256), 0, stream>>>(upd, gru_wih, gru_bih, fnull, gx, 384, 1536, 512, 0);
    sgemm<<<dim3(12, 6), dim3(256), 0, stream>>>(slots, gru_whh, gru_bhh, fnull, gh, 384, 1536, 512, 0);
    k_gruact<<<dim3(768), dim3(256), 0, stream>>>(gx, gh, slots);
    k_ln1<<<dim3(96), dim3(256), 0, stream>>>(slots, fln, ffnln_g, ffnln_b);
    sgemm<<<dim3(16, 6), dim3(256), 0, stream>>>(fln, ffn_w1, ffn_b1, fnull, f1, 384, 2048, 512, 1);
    sgemm<<<dim3(4, 6), dim3(256), 0, stream>>>(f1, ffn_w2, ffn_b2, slots, slots, 384, 512, 2048, 0);
  }

  sgemm<<<dim3(2, 6), dim3(256), 0, stream>>>(slots, sel_w1, sel_b1, fnull, hid, 384, 256, 512, 2);
  k_decide<<<dim3(32), dim3(64), 0, stream>>>(hid, sel_w2, sel_b2, slots, out);
}

// Round 2
// 901.256 us; speedup vs baseline: 1.7858x; 1.7858x over previous
//
#include <hip/hip_runtime.h>
#include <math.h>

typedef __attribute__((ext_vector_type(8))) short short8;
typedef __attribute__((ext_vector_type(4))) float f32x4;

typedef const __attribute__((address_space(1))) void gv_t;
typedef __attribute__((address_space(3))) void lv_t;

__device__ __forceinline__ float b2f(short u) {
  union { unsigned int i; float f; } c; c.i = ((unsigned int)(unsigned short)u) << 16; return c.f;
}
__device__ __forceinline__ short f2b(float f) {
  union { float f; unsigned int i; } c; c.f = f;
  unsigned int r = c.i + 0x7FFFu + ((c.i >> 16) & 1u);
  return (short)(r >> 16);
}

// ---------------- prep kernels ----------------

__global__ __launch_bounds__(256) void k_convA(const float* __restrict__ in, short* __restrict__ out, int n8) {
  int idx = blockIdx.x * 256 + threadIdx.x;
  if (idx >= n8) return;
  const float4* p = (const float4*)(in + (size_t)idx * 8);
  float4 a = p[0], b = p[1];
  short8 r;
  r[0]=f2b(a.x); r[1]=f2b(a.y); r[2]=f2b(a.z); r[3]=f2b(a.w);
  r[4]=f2b(b.x); r[5]=f2b(b.y); r[6]=f2b(b.z); r[7]=f2b(b.w);
  *(short8*)(out + (size_t)idx*8) = r;
}

// in: K x N fp32 row-major -> out: N x K bf16
__global__ __launch_bounds__(256) void k_transpose_bf(const float* __restrict__ in, short* __restrict__ out, int K, int N) {
  size_t idx = (size_t)blockIdx.x * 256 + threadIdx.x;
  if (idx >= (size_t)K * N) return;
  int kk = (int)(idx / N), n = (int)(idx % N);
  out[(size_t)n * K + kk] = f2b(in[idx]);
}

__global__ __launch_bounds__(256) void k_prep_kv(const float* __restrict__ wk, const float* __restrict__ wv, short* __restrict__ out) {
  int i = blockIdx.x * 256 + threadIdx.x;
  if (i >= 524288) return;
  int kk = i >> 10, n = i & 1023;
  float v = (n < 512) ? wk[kk*512 + n] : wv[kk*512 + (n - 512)];
  out[(size_t)n * 512 + kk] = f2b(v);
}

__global__ __launch_bounds__(256) void k_slots_init(const float* __restrict__ mu, const float* __restrict__ lsig,
                                                    const float* __restrict__ noise, float* __restrict__ slots,
                                                    short* __restrict__ slots_bf) {
  int idx = blockIdx.x * 256 + threadIdx.x; // 196608 total
  int sd = idx % 6144;
  float v = mu[sd] + __expf(lsig[sd]) * noise[idx];
  slots[idx] = v;
  slots_bf[idx] = f2b(v);
}

// ---------------- bf16 MFMA GEMM: C = act(A(MxK) @ Bt(NxK)^T + bias) (+res) ----------------
// 128x128 tile, BK=32, 256 threads (4 waves, 2x2 wave grid, 64x64 per wave)
// ACT: 0 none, 1 gelu(exact), 2 relu. OUTBF: write Cb bf16. RES: add res fp32.
// DUAL: write Cf fp32 AND Cb bf16.

template<int ACT, bool OUTBF, bool RES, bool DUAL>
__global__ __launch_bounds__(256) void gemm_t(
    const short* __restrict__ A, const short* __restrict__ Bt,
    const float* __restrict__ bias, const float* __restrict__ res,
    float* __restrict__ Cf, short* __restrict__ Cb,
    int M, int N, int K)
{
  __shared__ short As[128*32];
  __shared__ short Bs[128*32];
  const int t = threadIdx.x;
  const int lane = t & 63, wave = t >> 6;
  const int rowBase = blockIdx.y * 128, colBase = blockIdx.x * 128;
  const int wm = (wave >> 1) * 64, wn = (wave & 1) * 64;
  const int fr = lane & 15, fk = (lane >> 4) * 8;
  f32x4 acc[4][4] = {};
  const int c0 = t, c1 = 256 + t;
  const int r0 = c0 >> 2, k0 = (c0 & 3) * 8;
  const int r1 = c1 >> 2, k1 = (c1 & 3) * 8;
  for (int kb = 0; kb < K; kb += 32) {
    __syncthreads();
    __builtin_amdgcn_global_load_lds((gv_t*)(A + (size_t)(rowBase + r0)*K + kb + k0), (lv_t*)(As + c0*8), 16, 0, 0);
    __builtin_amdgcn_global_load_lds((gv_t*)(A + (size_t)(rowBase + r1)*K + kb + k1), (lv_t*)(As + c1*8), 16, 0, 0);
    __builtin_amdgcn_global_load_lds((gv_t*)(Bt + (size_t)(colBase + r0)*K + kb + k0), (lv_t*)(Bs + c0*8), 16, 0, 0);
    __builtin_amdgcn_global_load_lds((gv_t*)(Bt + (size_t)(colBase + r1)*K + kb + k1), (lv_t*)(Bs + c1*8), 16, 0, 0);
    __syncthreads();
    short8 af[4], bf[4];
    #pragma unroll
    for (int m = 0; m < 4; ++m) af[m] = *(const short8*)(As + (wm + m*16 + fr)*32 + fk);
    #pragma unroll
    for (int n = 0; n < 4; ++n) bf[n] = *(const short8*)(Bs + (wn + n*16 + fr)*32 + fk);
    #pragma unroll
    for (int m = 0; m < 4; ++m)
      #pragma unroll
      for (int n = 0; n < 4; ++n)
        acc[m][n] = __builtin_amdgcn_mfma_f32_16x16x32_bf16(af[m], bf[n], acc[m][n], 0, 0, 0);
  }
  const int cr = (lane >> 4) * 4, cc = lane & 15;
  #pragma unroll
  for (int m = 0; m < 4; ++m) {
    #pragma unroll
    for (int n = 0; n < 4; ++n) {
      int col = colBase + wn + n*16 + cc;
      float bv = bias ? bias[col] : 0.f;
      #pragma unroll
      for (int j = 0; j < 4; ++j) {
        int row = rowBase + wm + m*16 + cr + j;
        float v = acc[m][n][j] + bv;
        if (ACT == 1) v = 0.5f*v*(1.f + erff(v*0.70710678118f));
        else if (ACT == 2) v = fmaxf(v, 0.f);
        size_t idx = (size_t)row * N + col;
        if (RES) v += res[idx];
        if (DUAL) { Cf[idx] = v; Cb[idx] = f2b(v); }
        else if (OUTBF) Cb[idx] = f2b(v);
        else Cf[idx] = v;
      }
    }
  }
}

// ---------------- double layernorm: inp = LN2(LN1(y)) , bf16 in/out, wave per row ----------------

__global__ __launch_bounds__(256) void k_ln2(const short* __restrict__ y, short* __restrict__ inp,
    const float* __restrict__ g1, const float* __restrict__ b1,
    const float* __restrict__ g2, const float* __restrict__ b2)
{
  int t = threadIdx.x, lane = t & 63;
  int row = blockIdx.x * 4 + (t >> 6);
  const short8 raw = *(const short8*)(y + (size_t)row*512 + lane*8);
  float x[8];
  #pragma unroll
  for (int e = 0; e < 8; ++e) x[e] = b2f(raw[e]);
  float s = 0.f, ss = 0.f;
  #pragma unroll
  for (int e = 0; e < 8; ++e) { s += x[e]; ss += x[e]*x[e]; }
  #pragma unroll
  for (int m = 1; m < 64; m <<= 1) { s += __shfl_xor(s, m, 64); ss += __shfl_xor(ss, m, 64); }
  float mean = s * (1.f/512.f);
  float rs = rsqrtf(ss*(1.f/512.f) - mean*mean + 1e-5f);
  int c = lane * 8;
  #pragma unroll
  for (int e = 0; e < 8; ++e) x[e] = (x[e]-mean)*rs*g1[c+e] + b1[c+e];
  s = 0.f; ss = 0.f;
  #pragma unroll
  for (int e = 0; e < 8; ++e) { s += x[e]; ss += x[e]*x[e]; }
  #pragma unroll
  for (int m = 1; m < 64; m <<= 1) { s += __shfl_xor(s, m, 64); ss += __shfl_xor(ss, m, 64); }
  float mean2 = s * (1.f/512.f);
  float rs2 = rsqrtf(ss*(1.f/512.f) - mean2*mean2 + 1e-5f);
  short8 o;
  #pragma unroll
  for (int e = 0; e < 8; ++e) o[e] = f2b((x[e]-mean2)*rs2*g2[c+e] + b2[c+e]);
  *(short8*)(inp + (size_t)row*512 + lane*8) = o;
}

// ---------------- layernorm fp32 -> bf16, wave per row (512 cols) ----------------

__global__ __launch_bounds__(256) void k_lnb(const float* __restrict__ x, short* __restrict__ out,
    const float* __restrict__ g, const float* __restrict__ b)
{
  int t = threadIdx.x, lane = t & 63;
  int row = blockIdx.x * 4 + (t >> 6);
  const float* src = x + (size_t)row*512 + lane*8;
  float v[8];
  *(float4*)v = *(const float4*)src;
  *(float4*)(v+4) = *(const float4*)(src+4);
  float s = 0.f, ss = 0.f;
  #pragma unroll
  for (int e = 0; e < 8; ++e) { s += v[e]; ss += v[e]*v[e]; }
  #pragma unroll
  for (int m = 1; m < 64; m <<= 1) { s += __shfl_xor(s, m, 64); ss += __shfl_xor(ss, m, 64); }
  float mean = s * (1.f/512.f);
  float rs = rsqrtf(ss*(1.f/512.f) - mean*mean + 1e-5f);
  int c = lane * 8;
  short8 o;
  #pragma unroll
  for (int e = 0; e < 8; ++e) o[e] = f2b((v[e]-mean)*rs*g[c+e] + b[c+e]);
  *(short8*)(out + (size_t)row*512 + c) = o;
}

// ---------------- attention: dots = q . k * SCALE ----------------
// grid (jt=8, h=8, b=32); dots layout [b][j][s*8+h]

__global__ __launch_bounds__(256) void k_dots(const float* __restrict__ q, const short* __restrict__ kv,
                                              float* __restrict__ dots)
{
  __shared__ __align__(16) float qs[12][64];
  __shared__ float ks[128][65];
  int t = threadIdx.x;
  int jt = blockIdx.x, h = blockIdx.y, b = blockIdx.z;
  if (t < 192) {
    int s = t >> 4, d4 = (t & 15) * 4;
    *(float4*)&qs[s][d4] = *(const float4*)(q + (size_t)(b*12+s)*512 + h*64 + d4);
  }
  #pragma unroll
  for (int i = 0; i < 4; ++i) {
    int c = i*256 + t;
    int jj = c >> 3, seg = (c & 7) * 8;
    short8 raw = *(const short8*)(kv + ((size_t)(b*1024 + jt*128 + jj))*1024 + h*64 + seg);
    #pragma unroll
    for (int e = 0; e < 8; ++e) ks[jj][seg+e] = b2f(raw[e]);
  }
  __syncthreads();
  int jj = t & 127, sg = t >> 7;
  float d6[6] = {};
  for (int d = 0; d < 64; ++d) {
    float kvv = ks[jj][d];
    #pragma unroll
    for (int i = 0; i < 6; ++i) d6[i] += qs[sg*6+i][d] * kvv;
  }
  float* o = dots + ((size_t)(b*1024 + jt*128 + jj))*96 + h;
  #pragma unroll
  for (int i = 0; i < 6; ++i) o[(sg*6+i)*8] = d6[i] * 0.125f;
}

// ---------------- softmax over the 96 (s,h) axis, in place; optional attn_out ----------------

__global__ __launch_bounds__(256) void k_soft(float* __restrict__ dots, float* __restrict__ aout)
{
  int t = threadIdx.x, b = blockIdx.y;
  int j = blockIdx.x * 256 + t;
  float* p = dots + ((size_t)(b*1024 + j)) * 96;
  float v[96];
  #pragma unroll
  for (int i = 0; i < 24; ++i) *(float4*)&v[i*4] = *(const float4*)(p + i*4);
  float mx = v[0];
  #pragma unroll
  for (int i = 1; i < 96; ++i) mx = fmaxf(mx, v[i]);
  float sum = 0.f;
  #pragma unroll
  for (int i = 0; i < 96; ++i) { v[i] = __expf(v[i]-mx); sum += v[i]; }
  float inv = 1.f/sum;
  #pragma unroll
  for (int i = 0; i < 96; ++i) v[i] *= inv;
  #pragma unroll
  for (int i = 0; i < 24; ++i) *(float4*)(p + i*4) = *(float4*)&v[i*4];
  if (aout) {
    #pragma unroll
    for (int s = 0; s < 8; ++s) {
      float m = 0.f;
      #pragma unroll
      for (int hh = 0; hh < 8; ++hh) m += v[s*8+hh];
      aout[(size_t)(b*8+s)*1024 + j] = m * 0.125f;
    }
  }
}

// ---------------- vsum[b][h*64+d] = sum_j v ----------------

__global__ __launch_bounds__(256) void k_vsum(const short* __restrict__ kv, float* __restrict__ vsum)
{
  __shared__ float part[128];
  int t = threadIdx.x;
  int cq = blockIdx.x, b = blockIdx.y;
  int c = cq*128 + (t & 127), jh = t >> 7;
  float acc = 0.f;
  for (int j = jh*512; j < jh*512 + 512; ++j)
    acc += b2f(kv[((size_t)(b*1024 + j))*1024 + 512 + c]);
  if (jh == 1) part[t & 127] = acc;
  __syncthreads();
  if (jh == 0) vsum[b*512 + c] = acc + part[t & 127];
}

// ---------------- upd = (sum_j v*attn + 1e-8*vsum) / (den + 1e-8) ; grid (h=8, b=32) ----------------
// writes bf16

__global__ __launch_bounds__(256) void k_upd(const float* __restrict__ dots, const short* __restrict__ kv,
    const float* __restrict__ vsum, short* __restrict__ upd)
{
  __shared__ float atts[12][129];
  __shared__ float vs[128][65];
  __shared__ float den_s[12];
  int t = threadIdx.x;
  int h = blockIdx.x, b = blockIdx.y;
  int d = t & 63, sq = t >> 6;
  int jj2 = t & 127, sg = t >> 7;
  float acc[3] = {0.f, 0.f, 0.f};
  float myden = 0.f;
  for (int jt = 0; jt < 8; ++jt) {
    __syncthreads();
    const float* src = dots + ((size_t)(b*1024 + jt*128 + jj2))*96 + h;
    #pragma unroll
    for (int i = 0; i < 6; ++i) atts[sg*6+i][jj2] = src[(sg*6+i)*8];
    #pragma unroll
    for (int i = 0; i < 4; ++i) {
      int c = i*256 + t;
      int jj = c >> 3, seg = (c & 7)*8;
      short8 raw = *(const short8*)(kv + ((size_t)(b*1024 + jt*128 + jj))*1024 + 512 + h*64 + seg);
      #pragma unroll
      for (int e = 0; e < 8; ++e) vs[jj][seg+e] = b2f(raw[e]);
    }
    __syncthreads();
    for (int jj = 0; jj < 128; ++jj) {
      float vv = vs[jj][d];
      #pragma unroll
      for (int i = 0; i < 3; ++i) acc[i] += atts[sq + 4*i][jj] * vv;
    }
    if (t < 12) {
      float ls = 0.f;
      for (int jj = 0; jj < 128; ++jj) ls += atts[t][jj];
      myden += ls;
    }
  }
  __syncthreads();
  if (t < 12) den_s[t] = myden;
  __syncthreads();
  #pragma unroll
  for (int i = 0; i < 3; ++i) {
    int s = sq + 4*i;
    int col = h*64 + d;
    float r = (acc[i] + 1e-8f * vsum[b*512 + col]) / (den_s[s] + 1e-8f);
    upd[(size_t)(b*12+s)*512 + col] = f2b(r);
  }
}

// ---------------- GRU gate combine (reads gx, gh; updates slots fp32 in place) ----------------

__global__ __launch_bounds__(256) void k_gruact(const float* __restrict__ gx, const float* __restrict__ gh,
                                                float* __restrict__ slots)
{
  int idx = blockIdx.x*256 + threadIdx.x; // 196608
  int row = idx >> 9, c = idx & 511;
  const float* gxr = gx + (size_t)row*1536;
  const float* ghr = gh + (size_t)row*1536;
  float r = 1.f/(1.f + __expf(-(gxr[c] + ghr[c])));
  float z = 1.f/(1.f + __expf(-(gxr[512+c] + ghr[512+c])));
  float n = tanhf(gxr[1024+c] + r*ghr[1024+c]);
  float h = slots[idx];
  slots[idx] = (1.f - z)*n + z*h;
}

// ---------------- selector head: logits, decision logic, obj write ----------------

__global__ __launch_bounds__(64) void k_decide(const float* __restrict__ hid, const float* __restrict__ w2,
    const float* __restrict__ b2, const float* __restrict__ slots, float* __restrict__ out)
{
  __shared__ float lg[16];
  __shared__ float dec[8];
  int b = blockIdx.x, t = threadIdx.x;
  if (t < 16) {
    int s = t >> 1, cl = t & 1;
    const float* hr = hid + (size_t)(b*12+s)*256;
    float a = b2[cl];
    for (int k = 0; k < 256; ++k) a += hr[k] * w2[k*2+cl];
    lg[t] = a;
  }
  __syncthreads();
  if (t == 0) {
    float d0[8]; float tot = 0.f;
    #pragma unroll
    for (int s = 0; s < 8; ++s) { d0[s] = (lg[2*s+1] > lg[2*s]) ? 1.f : 0.f; tot += d0[s]; }
    float needed = fmaxf(0.f, 2.f - tot);
    float cum = 0.f;
    #pragma unroll
    for (int s = 0; s < 8; ++s) {
      cum += 1.f - d0[s];
      float add = (d0[s] == 0.f && cum <= needed) ? 1.f : 0.f;
      float dd = d0[s] + add;
      dec[s] = dd;
      out[131072 + b*8 + s] = dd;
    }
  }
  __syncthreads();
  for (int i = 0; i < 64; ++i) {
    int idx = i*64 + t;
    int s = idx >> 9, c = idx & 511;
    out[(size_t)(b*8+s)*512 + c] = slots[(size_t)(b*12+s)*512 + c] * dec[s];
  }
}

// ---------------- host ----------------

extern "C" void kernel_launch(void* const* d_in, const int* in_sizes, int n_in,
                              void* d_out, int out_size, void* d_ws, size_t ws_size,
                              hipStream_t stream) {
  const float* features = (const float*)d_in[0];
  const float* noise    = (const float*)d_in[1];
  const float* w_in     = (const float*)d_in[2];
  const float* b_in     = (const float*)d_in[3];
  const float* ln1_g    = (const float*)d_in[4];
  const float* ln1_b    = (const float*)d_in[5];
  const float* slot_mu  = (const float*)d_in[6];
  const float* slot_ls  = (const float*)d_in[7];
  const float* wq       = (const float*)d_in[8];
  const float* wk       = (const float*)d_in[9];
  const float* wv       = (const float*)d_in[10];
  const float* gru_wih  = (const float*)d_in[11];
  const float* gru_whh  = (const float*)d_in[12];
  const float* gru_bih  = (const float*)d_in[13];
  const float* gru_bhh  = (const float*)d_in[14];
  const float* nslots_g = (const float*)d_in[15];
  const float* nslots_b = (const float*)d_in[16];
  const float* ninput_g = (const float*)d_in[17];
  const float* ninput_b = (const float*)d_in[18];
  const float* ffnln_g  = (const float*)d_in[19];
  const float* ffnln_b  = (const float*)d_in[20];
  const float* ffn_w1   = (const float*)d_in[21];
  const float* ffn_b1   = (const float*)d_in[22];
  const float* ffn_w2   = (const float*)d_in[23];
  const float* ffn_b2   = (const float*)d_in[24];
  const float* sel_w1   = (const float*)d_in[25];
  const float* sel_b1   = (const float*)d_in[26];
  const float* sel_w2   = (const float*)d_in[27];
  const float* sel_b2   = (const float*)d_in[28];
  float* out = (float*)d_out;
  float* fnull = (float*)nullptr;
  short* snull = (short*)nullptr;

  char* w = (char*)d_ws;
  size_t off = 0;
  auto alloc = [&](size_t n) { char* p = w + off; off = (off + n + 255) & ~255ULL; return p; };
  short* Abf   = (short*)alloc(75497472);   // features bf16 (32768x1152); later reused as kv
  short* kv    = Abf;                       // (32768x1024) bf16, written after Abf is dead
  short* ybf   = (short*)alloc(33554432);   // gemm1 out bf16; later reused as dots
  float* dots  = (float*)ybf;               // (32*1024*96) fp32 = 12.6MB
  short* inp   = (short*)alloc(33554432);   // LN'd input bf16
  short* Bt1   = (short*)alloc(1179648);    // w_in^T bf16 (512x1152)
  short* Btkv  = (short*)alloc(1048576);    // [wk|wv]^T bf16 (1024x512)
  short* wq_t  = (short*)alloc(524288);     // (512x512)
  short* wih_t = (short*)alloc(1572864);    // (1536x512)
  short* whh_t = (short*)alloc(1572864);    // (1536x512)
  short* w1_t  = (short*)alloc(2097152);    // (2048x512)
  short* w2_t  = (short*)alloc(2097152);    // (512x2048)
  short* sl1_t = (short*)alloc(262144);     // (256x512)
  float* slots = (float*)alloc(786432);
  short* slotsb= (short*)alloc(393216);
  short* sn    = (short*)alloc(393216);
  float* qb    = (float*)alloc(786432);
  short* updb  = (short*)alloc(393216);
  float* gx    = (float*)alloc(2359296);
  float* gh    = (float*)alloc(2359296);
  short* fln   = (short*)alloc(393216);
  short* f1    = (short*)alloc(1572864);
  float* hid   = (float*)alloc(393216);
  float* vsum  = (float*)alloc(65536);
  (void)ws_size; (void)in_sizes; (void)n_in; (void)out_size;

  k_convA<<<dim3(18432), dim3(256), 0, stream>>>(features, Abf, 4718592);
  k_transpose_bf<<<dim3(2304), dim3(256), 0, stream>>>(w_in, Bt1, 1152, 512);
  k_prep_kv<<<dim3(2048), dim3(256), 0, stream>>>(wk, wv, Btkv);
  k_transpose_bf<<<dim3(1024), dim3(256), 0, stream>>>(wq, wq_t, 512, 512);
  k_transpose_bf<<<dim3(3072), dim3(256), 0, stream>>>(gru_wih, wih_t, 512, 1536);
  k_transpose_bf<<<dim3(3072), dim3(256), 0, stream>>>(gru_whh, whh_t, 512, 1536);
  k_transpose_bf<<<dim3(4096), dim3(256), 0, stream>>>(ffn_w1, w1_t, 512, 2048);
  k_transpose_bf<<<dim3(4096), dim3(256), 0, stream>>>(ffn_w2, w2_t, 2048, 512);
  k_transpose_bf<<<dim3(512), dim3(256), 0, stream>>>(sel_w1, sl1_t, 512, 256);
  k_slots_init<<<dim3(768), dim3(256), 0, stream>>>(slot_mu, slot_ls, noise, slots, slotsb);

  // phase A: y = features @ w_in + b_in ; inp = LN2(LN1(y)) ; kv = inp @ [wk|wv]
  gemm_t<0,true,false,false><<<dim3(4, 256), dim3(256), 0, stream>>>(Abf, Bt1, b_in, fnull, fnull, ybf, 32768, 512, 1152);
  k_ln2<<<dim3(8192), dim3(256), 0, stream>>>(ybf, inp, ln1_g, ln1_b, ninput_g, ninput_b);
  gemm_t<0,true,false,false><<<dim3(8, 256), dim3(256), 0, stream>>>(inp, Btkv, fnull, fnull, fnull, kv, 32768, 1024, 512);
  k_vsum<<<dim3(4, 32), dim3(256), 0, stream>>>(kv, vsum);

  for (int it = 0; it < 3; ++it) {
    k_lnb<<<dim3(96), dim3(256), 0, stream>>>(slots, sn, nslots_g, nslots_b);
    gemm_t<0,false,false,false><<<dim3(4, 3), dim3(256), 0, stream>>>(sn, wq_t, fnull, fnull, qb, snull, 384, 512, 512);
    k_dots<<<dim3(8, 8, 32), dim3(256), 0, stream>>>(qb, kv, dots);
    k_soft<<<dim3(4, 32), dim3(256), 0, stream>>>(dots, it == 2 ? out + 131328 : fnull);
    k_upd<<<dim3(8, 32), dim3(256), 0, stream>>>(dots, kv, vsum, updb);
    gemm_t<0,false,false,false><<<dim3(12, 3), dim3(256), 0, stream>>>(updb, wih_t, gru_bih, fnull, gx, snull, 384, 1536, 512);
    gemm_t<0,false,false,false><<<dim3(12, 3), dim3(256), 0, stream>>>(slotsb, whh_t, gru_bhh, fnull, gh, snull, 384, 1536, 512);
    k_gruact<<<dim3(768), dim3(256), 0, stream>>>(gx, gh, slots);
    k_lnb<<<dim3(96), dim3(256), 0, stream>>>(slots, fln, ffnln_g, ffnln_b);
    gemm_t<1,true,false,false><<<dim3(16, 3), dim3(256), 0, stream>>>(fln, w1_t, ffn_b1, fnull, fnull, f1, 384, 2048, 512);
    gemm_t<0,false,true,true><<<dim3(4, 3), dim3(256), 0, stream>>>(f1, w2_t, ffn_b2, slots, slots, slotsb, 384, 512, 2048);
  }

  gemm_t<2,false,false,false><<<dim3(2, 3), dim3(256), 0, stream>>>(slotsb, sl1_t, sel_b1, fnull, hid, snull, 384, 256, 512);
  k_decide<<<dim3(32), dim3(64), 0, stream>>>(hid, sel_w2, sel_b2, slots, out);
}

// Round 3
// 853.945 us; speedup vs baseline: 1.8848x; 1.0554x over previous
//
#include <hip/hip_runtime.h>
#include <math.h>

typedef __attribute__((ext_vector_type(8))) short short8;
typedef __attribute__((ext_vector_type(4))) float f32x4;

typedef const __attribute__((address_space(1))) void gv_t;
typedef __attribute__((address_space(3))) void lv_t;

__device__ __forceinline__ float b2f(short u) {
  union { unsigned int i; float f; } c; c.i = ((unsigned int)(unsigned short)u) << 16; return c.f;
}
__device__ __forceinline__ short f2b(float f) {
  union { float f; unsigned int i; } c; c.f = f;
  unsigned int r = c.i + 0x7FFFu + ((c.i >> 16) & 1u);
  return (short)(r >> 16);
}

// ---------------- prep kernels ----------------

__global__ __launch_bounds__(256) void k_convA(const float* __restrict__ in, short* __restrict__ out, int n8) {
  int idx = blockIdx.x * 256 + threadIdx.x;
  if (idx >= n8) return;
  const float4* p = (const float4*)(in + (size_t)idx * 8);
  float4 a = p[0], b = p[1];
  short8 r;
  r[0]=f2b(a.x); r[1]=f2b(a.y); r[2]=f2b(a.z); r[3]=f2b(a.w);
  r[4]=f2b(b.x); r[5]=f2b(b.y); r[6]=f2b(b.z); r[7]=f2b(b.w);
  *(short8*)(out + (size_t)idx*8) = r;
}

// in: K x N fp32 row-major -> out: N x K bf16
__global__ __launch_bounds__(256) void k_transpose_bf(const float* __restrict__ in, short* __restrict__ out, int K, int N) {
  size_t idx = (size_t)blockIdx.x * 256 + threadIdx.x;
  if (idx >= (size_t)K * N) return;
  int kk = (int)(idx / N), n = (int)(idx % N);
  out[(size_t)n * K + kk] = f2b(in[idx]);
}

__global__ __launch_bounds__(256) void k_prep_kv(const float* __restrict__ wk, const float* __restrict__ wv, short* __restrict__ out) {
  int i = blockIdx.x * 256 + threadIdx.x;
  if (i >= 524288) return;
  int kk = i >> 10, n = i & 1023;
  float v = (n < 512) ? wk[kk*512 + n] : wv[kk*512 + (n - 512)];
  out[(size_t)n * 512 + kk] = f2b(v);
}

__global__ __launch_bounds__(256) void k_slots_init(const float* __restrict__ mu, const float* __restrict__ lsig,
                                                    const float* __restrict__ noise, float* __restrict__ slots,
                                                    short* __restrict__ slots_bf) {
  int idx = blockIdx.x * 256 + threadIdx.x; // 196608 total
  int sd = idx % 6144;
  float v = mu[sd] + __expf(lsig[sd]) * noise[idx];
  slots[idx] = v;
  slots_bf[idx] = f2b(v);
}

// ---------------- bf16 MFMA GEMM: C = act(A(MxK) @ Bt(NxK)^T + bias) (+res) ----------------
// 128x128 tile, BK=64, 256 threads (4 waves, 2x2 wave grid, 64x64 per wave).
// 1D grid, col-tile-fastest, bijective XCD swizzle (T1/m204) so each XCD owns
// contiguous row-tiles -> A fetched once per XCD L2.
// LDS: linear dest for global_load_lds + inverse-swizzled GLOBAL source +
// XOR-swizzled fragment reads (m201 both-sides pattern) -> conflict-free ds_read_b128.
// ACT: 0 none, 1 gelu(exact), 2 relu. OUTBF: write Cb bf16. RES: add res fp32.
// DUAL: write Cf fp32 AND Cb bf16.

template<int ACT, bool OUTBF, bool RES, bool DUAL>
__global__ __launch_bounds__(256) void gemm_t(
    const short* __restrict__ A, const short* __restrict__ Bt,
    const float* __restrict__ bias, const float* __restrict__ res,
    float* __restrict__ Cf, short* __restrict__ Cb,
    int M, int N, int K)
{
  __shared__ short As[128*64];
  __shared__ short Bs[128*64];
  const int t = threadIdx.x;
  const int lane = t & 63, wave = t >> 6;

  // --- T1 bijective XCD swizzle (m204) ---
  const int nwg = gridDim.x;
  const int gridX = N >> 7;
  {
  }
  const int orig = blockIdx.x;
  const int q = nwg >> 3, r = nwg & 7, xcd = orig & 7, base = orig >> 3;
  const int wgid = (xcd < r ? xcd*(q+1) : r*(q+1) + (xcd - r)*q) + base;
  const int bx = wgid % gridX, by = wgid / gridX;

  const int rowBase = by * 128, colBase = bx * 128;
  const int wm = (wave >> 1) * 64, wn = (wave & 1) * 64;
  const int fr = lane & 15, kcf = lane >> 4;   // fragment row-in-16, k-chunk (16B units)
  f32x4 acc[4][4] = {};

  // staging: 1024 16B-chunks per matrix per K-step; thread t takes c = i*256+t.
  // LDS dest linear (wave-uniform + lane*16); global col-chunk = cc ^ (r&7).
  int srow[4], scol[4];
  #pragma unroll
  for (int i = 0; i < 4; ++i) {
    int c = i*256 + t;
    srow[i] = c >> 3;
    int cc = c & 7;
    scol[i] = (cc ^ (srow[i] & 7)) * 8;
  }

  for (int kb = 0; kb < K; kb += 64) {
    __syncthreads();
    #pragma unroll
    for (int i = 0; i < 4; ++i) {
      int c = i*256 + t;
      __builtin_amdgcn_global_load_lds((gv_t*)(A + (size_t)(rowBase + srow[i])*K + kb + scol[i]), (lv_t*)(As + c*8), 16, 0, 0);
      __builtin_amdgcn_global_load_lds((gv_t*)(Bt + (size_t)(colBase + srow[i])*K + kb + scol[i]), (lv_t*)(Bs + c*8), 16, 0, 0);
    }
    __syncthreads();
    #pragma unroll
    for (int ks = 0; ks < 2; ++ks) {
      short8 af[4], bf[4];
      #pragma unroll
      for (int m = 0; m < 4; ++m) {
        int row = wm + m*16 + fr;
        int kc = ks*4 + kcf;
        af[m] = *(const short8*)(As + row*64 + (kc ^ (row & 7))*8);
      }
      #pragma unroll
      for (int n = 0; n < 4; ++n) {
        int row = wn + n*16 + fr;
        int kc = ks*4 + kcf;
        bf[n] = *(const short8*)(Bs + row*64 + (kc ^ (row & 7))*8);
      }
      #pragma unroll
      for (int m = 0; m < 4; ++m)
        #pragma unroll
        for (int n = 0; n < 4; ++n)
          acc[m][n] = __builtin_amdgcn_mfma_f32_16x16x32_bf16(af[m], bf[n], acc[m][n], 0, 0, 0);
    }
  }
  const int cr = (lane >> 4) * 4, cc2 = lane & 15;
  #pragma unroll
  for (int m = 0; m < 4; ++m) {
    #pragma unroll
    for (int n = 0; n < 4; ++n) {
      int col = colBase + wn + n*16 + cc2;
      float bv = bias ? bias[col] : 0.f;
      #pragma unroll
      for (int j = 0; j < 4; ++j) {
        int row = rowBase + wm + m*16 + cr + j;
        float v = acc[m][n][j] + bv;
        if (ACT == 1) v = 0.5f*v*(1.f + erff(v*0.70710678118f));
        else if (ACT == 2) v = fmaxf(v, 0.f);
        size_t idx = (size_t)row * N + col;
        if (RES) v += res[idx];
        if (DUAL) { Cf[idx] = v; Cb[idx] = f2b(v); }
        else if (OUTBF) Cb[idx] = f2b(v);
        else Cf[idx] = v;
      }
    }
  }
}

// ---------------- double layernorm: inp = LN2(LN1(y)) , bf16 in/out, wave per row ----------------

__global__ __launch_bounds__(256) void k_ln2(const short* __restrict__ y, short* __restrict__ inp,
    const float* __restrict__ g1, const float* __restrict__ b1,
    const float* __restrict__ g2, const float* __restrict__ b2)
{
  int t = threadIdx.x, lane = t & 63;
  int row = blockIdx.x * 4 + (t >> 6);
  const short8 raw = *(const short8*)(y + (size_t)row*512 + lane*8);
  float x[8];
  #pragma unroll
  for (int e = 0; e < 8; ++e) x[e] = b2f(raw[e]);
  float s = 0.f, ss = 0.f;
  #pragma unroll
  for (int e = 0; e < 8; ++e) { s += x[e]; ss += x[e]*x[e]; }
  #pragma unroll
  for (int m = 1; m < 64; m <<= 1) { s += __shfl_xor(s, m, 64); ss += __shfl_xor(ss, m, 64); }
  float mean = s * (1.f/512.f);
  float rs = rsqrtf(ss*(1.f/512.f) - mean*mean + 1e-5f);
  int c = lane * 8;
  #pragma unroll
  for (int e = 0; e < 8; ++e) x[e] = (x[e]-mean)*rs*g1[c+e] + b1[c+e];
  s = 0.f; ss = 0.f;
  #pragma unroll
  for (int e = 0; e < 8; ++e) { s += x[e]; ss += x[e]*x[e]; }
  #pragma unroll
  for (int m = 1; m < 64; m <<= 1) { s += __shfl_xor(s, m, 64); ss += __shfl_xor(ss, m, 64); }
  float mean2 = s * (1.f/512.f);
  float rs2 = rsqrtf(ss*(1.f/512.f) - mean2*mean2 + 1e-5f);
  short8 o;
  #pragma unroll
  for (int e = 0; e < 8; ++e) o[e] = f2b((x[e]-mean2)*rs2*g2[c+e] + b2[c+e]);
  *(short8*)(inp + (size_t)row*512 + lane*8) = o;
}

// ---------------- layernorm fp32 -> bf16, wave per row (512 cols) ----------------

__global__ __launch_bounds__(256) void k_lnb(const float* __restrict__ x, short* __restrict__ out,
    const float* __restrict__ g, const float* __restrict__ b)
{
  int t = threadIdx.x, lane = t & 63;
  int row = blockIdx.x * 4 + (t >> 6);
  const float* src = x + (size_t)row*512 + lane*8;
  float v[8];
  *(float4*)v = *(const float4*)src;
  *(float4*)(v+4) = *(const float4*)(src+4);
  float s = 0.f, ss = 0.f;
  #pragma unroll
  for (int e = 0; e < 8; ++e) { s += v[e]; ss += v[e]*v[e]; }
  #pragma unroll
  for (int m = 1; m < 64; m <<= 1) { s += __shfl_xor(s, m, 64); ss += __shfl_xor(ss, m, 64); }
  float mean = s * (1.f/512.f);
  float rs = rsqrtf(ss*(1.f/512.f) - mean*mean + 1e-5f);
  int c = lane * 8;
  short8 o;
  #pragma unroll
  for (int e = 0; e < 8; ++e) o[e] = f2b((v[e]-mean)*rs*g[c+e] + b[c+e]);
  *(short8*)(out + (size_t)row*512 + c) = o;
}

// ---------------- attention: dots = q . k * SCALE ----------------
// grid (jt=8, h=8, b=32); dots layout [b][j][s*8+h]

__global__ __launch_bounds__(256) void k_dots(const float* __restrict__ q, const short* __restrict__ kv,
                                              float* __restrict__ dots)
{
  __shared__ __align__(16) float qs[12][64];
  __shared__ float ks[128][65];
  int t = threadIdx.x;
  int jt = blockIdx.x, h = blockIdx.y, b = blockIdx.z;
  if (t < 192) {
    int s = t >> 4, d4 = (t & 15) * 4;
    *(float4*)&qs[s][d4] = *(const float4*)(q + (size_t)(b*12+s)*512 + h*64 + d4);
  }
  #pragma unroll
  for (int i = 0; i < 4; ++i) {
    int c = i*256 + t;
    int jj = c >> 3, seg = (c & 7) * 8;
    short8 raw = *(const short8*)(kv + ((size_t)(b*1024 + jt*128 + jj))*1024 + h*64 + seg);
    #pragma unroll
    for (int e = 0; e < 8; ++e) ks[jj][seg+e] = b2f(raw[e]);
  }
  __syncthreads();
  int jj = t & 127, sg = t >> 7;
  float d6[6] = {};
  for (int d = 0; d < 64; ++d) {
    float kvv = ks[jj][d];
    #pragma unroll
    for (int i = 0; i < 6; ++i) d6[i] += qs[sg*6+i][d] * kvv;
  }
  float* o = dots + ((size_t)(b*1024 + jt*128 + jj))*96 + h;
  #pragma unroll
  for (int i = 0; i < 6; ++i) o[(sg*6+i)*8] = d6[i] * 0.125f;
}

// ---------------- softmax over the 96 (s,h) axis, in place; optional attn_out ----------------

__global__ __launch_bounds__(256) void k_soft(float* __restrict__ dots, float* __restrict__ aout)
{
  int t = threadIdx.x, b = blockIdx.y;
  int j = blockIdx.x * 256 + t;
  float* p = dots + ((size_t)(b*1024 + j)) * 96;
  float v[96];
  #pragma unroll
  for (int i = 0; i < 24; ++i) *(float4*)&v[i*4] = *(const float4*)(p + i*4);
  float mx = v[0];
  #pragma unroll
  for (int i = 1; i < 96; ++i) mx = fmaxf(mx, v[i]);
  float sum = 0.f;
  #pragma unroll
  for (int i = 0; i < 96; ++i) { v[i] = __expf(v[i]-mx); sum += v[i]; }
  float inv = 1.f/sum;
  #pragma unroll
  for (int i = 0; i < 96; ++i) v[i] *= inv;
  #pragma unroll
  for (int i = 0; i < 24; ++i) *(float4*)(p + i*4) = *(float4*)&v[i*4];
  if (aout) {
    #pragma unroll
    for (int s = 0; s < 8; ++s) {
      float m = 0.f;
      #pragma unroll
      for (int hh = 0; hh < 8; ++hh) m += v[s*8+hh];
      aout[(size_t)(b*8+s)*1024 + j] = m * 0.125f;
    }
  }
}

// ---------------- vsum[b][h*64+d] = sum_j v ----------------

__global__ __launch_bounds__(256) void k_vsum(const short* __restrict__ kv, float* __restrict__ vsum)
{
  __shared__ float part[128];
  int t = threadIdx.x;
  int cq = blockIdx.x, b = blockIdx.y;
  int c = cq*128 + (t & 127), jh = t >> 7;
  float acc = 0.f;
  for (int j = jh*512; j < jh*512 + 512; ++j)
    acc += b2f(kv[((size_t)(b*1024 + j))*1024 + 512 + c]);
  if (jh == 1) part[t & 127] = acc;
  __syncthreads();
  if (jh == 0) vsum[b*512 + c] = acc + part[t & 127];
}

// ---------------- upd = (sum_j v*attn + 1e-8*vsum) / (den + 1e-8) ; grid (h=8, b=32) ----------------
// writes bf16

__global__ __launch_bounds__(256) void k_upd(const float* __restrict__ dots, const short* __restrict__ kv,
    const float* __restrict__ vsum, short* __restrict__ upd)
{
  __shared__ float atts[12][129];
  __shared__ float vs[128][65];
  __shared__ float den_s[12];
  int t = threadIdx.x;
  int h = blockIdx.x, b = blockIdx.y;
  int d = t & 63, sq = t >> 6;
  int jj2 = t & 127, sg = t >> 7;
  float acc[3] = {0.f, 0.f, 0.f};
  float myden = 0.f;
  for (int jt = 0; jt < 8; ++jt) {
    __syncthreads();
    const float* src = dots + ((size_t)(b*1024 + jt*128 + jj2))*96 + h;
    #pragma unroll
    for (int i = 0; i < 6; ++i) atts[sg*6+i][jj2] = src[(sg*6+i)*8];
    #pragma unroll
    for (int i = 0; i < 4; ++i) {
      int c = i*256 + t;
      int jj = c >> 3, seg = (c & 7)*8;
      short8 raw = *(const short8*)(kv + ((size_t)(b*1024 + jt*128 + jj))*1024 + 512 + h*64 + seg);
      #pragma unroll
      for (int e = 0; e < 8; ++e) vs[jj][seg+e] = b2f(raw[e]);
    }
    __syncthreads();
    for (int jj = 0; jj < 128; ++jj) {
      float vv = vs[jj][d];
      #pragma unroll
      for (int i = 0; i < 3; ++i) acc[i] += atts[sq + 4*i][jj] * vv;
    }
    if (t < 12) {
      float ls = 0.f;
      for (int jj = 0; jj < 128; ++jj) ls += atts[t][jj];
      myden += ls;
    }
  }
  __syncthreads();
  if (t < 12) den_s[t] = myden;
  __syncthreads();
  #pragma unroll
  for (int i = 0; i < 3; ++i) {
    int s = sq + 4*i;
    int col = h*64 + d;
    float r = (acc[i] + 1e-8f * vsum[b*512 + col]) / (den_s[s] + 1e-8f);
    upd[(size_t)(b*12+s)*512 + col] = f2b(r);
  }
}

// ---------------- GRU gate combine (reads gx, gh; updates slots fp32 in place) ----------------

__global__ __launch_bounds__(256) void k_gruact(const float* __restrict__ gx, const float* __restrict__ gh,
                                                float* __restrict__ slots)
{
  int idx = blockIdx.x*256 + threadIdx.x; // 196608
  int row = idx >> 9, c = idx & 511;
  const float* gxr = gx + (size_t)row*1536;
  const float* ghr = gh + (size_t)row*1536;
  float r = 1.f/(1.f + __expf(-(gxr[c] + ghr[c])));
  float z = 1.f/(1.f + __expf(-(gxr[512+c] + ghr[512+c])));
  float n = tanhf(gxr[1024+c] + r*ghr[1024+c]);
  float h = slots[idx];
  slots[idx] = (1.f - z)*n + z*h;
}

// ---------------- selector head: logits, decision logic, obj write ----------------

__global__ __launch_bounds__(64) void k_decide(const float* __restrict__ hid, const float* __restrict__ w2,
    const float* __restrict__ b2, const float* __restrict__ slots, float* __restrict__ out)
{
  __shared__ float lg[16];
  __shared__ float dec[8];
  int b = blockIdx.x, t = threadIdx.x;
  if (t < 16) {
    int s = t >> 1, cl = t & 1;
    const float* hr = hid + (size_t)(b*12+s)*256;
    float a = b2[cl];
    for (int k = 0; k < 256; ++k) a += hr[k] * w2[k*2+cl];
    lg[t] = a;
  }
  __syncthreads();
  if (t == 0) {
    float d0[8]; float tot = 0.f;
    #pragma unroll
    for (int s = 0; s < 8; ++s) { d0[s] = (lg[2*s+1] > lg[2*s]) ? 1.f : 0.f; tot += d0[s]; }
    float needed = fmaxf(0.f, 2.f - tot);
    float cum = 0.f;
    #pragma unroll
    for (int s = 0; s < 8; ++s) {
      cum += 1.f - d0[s];
      float add = (d0[s] == 0.f && cum <= needed) ? 1.f : 0.f;
      float dd = d0[s] + add;
      dec[s] = dd;
      out[131072 + b*8 + s] = dd;
    }
  }
  __syncthreads();
  for (int i = 0; i < 64; ++i) {
    int idx = i*64 + t;
    int s = idx >> 9, c = idx & 511;
    out[(size_t)(b*8+s)*512 + c] = slots[(size_t)(b*12+s)*512 + c] * dec[s];
  }
}

// ---------------- host ----------------

extern "C" void kernel_launch(void* const* d_in, const int* in_sizes, int n_in,
                              void* d_out, int out_size, void* d_ws, size_t ws_size,
                              hipStream_t stream) {
  const float* features = (const float*)d_in[0];
  const float* noise    = (const float*)d_in[1];
  const float* w_in     = (const float*)d_in[2];
  const float* b_in     = (const float*)d_in[3];
  const float* ln1_g    = (const float*)d_in[4];
  const float* ln1_b    = (const float*)d_in[5];
  const float* slot_mu  = (const float*)d_in[6];
  const float* slot_ls  = (const float*)d_in[7];
  const float* wq       = (const float*)d_in[8];
  const float* wk       = (const float*)d_in[9];
  const float* wv       = (const float*)d_in[10];
  const float* gru_wih  = (const float*)d_in[11];
  const float* gru_whh  = (const float*)d_in[12];
  const float* gru_bih  = (const float*)d_in[13];
  const float* gru_bhh  = (const float*)d_in[14];
  const float* nslots_g = (const float*)d_in[15];
  const float* nslots_b = (const float*)d_in[16];
  const float* ninput_g = (const float*)d_in[17];
  const float* ninput_b = (const float*)d_in[18];
  const float* ffnln_g  = (const float*)d_in[19];
  const float* ffnln_b  = (const float*)d_in[20];
  const float* ffn_w1   = (const float*)d_in[21];
  const float* ffn_b1   = (const float*)d_in[22];
  const float* ffn_w2   = (const float*)d_in[23];
  const float* ffn_b2   = (const float*)d_in[24];
  const float* sel_w1   = (const float*)d_in[25];
  const float* sel_b1   = (const float*)d_in[26];
  const float* sel_w2   = (const float*)d_in[27];
  const float* sel_b2   = (const float*)d_in[28];
  float* out = (float*)d_out;
  float* fnull = (float*)nullptr;
  short* snull = (short*)nullptr;

  char* w = (char*)d_ws;
  size_t off = 0;
  auto alloc = [&](size_t n) { char* p = w + off; off = (off + n + 255) & ~255ULL; return p; };
  short* Abf   = (short*)alloc(75497472);   // features bf16 (32768x1152); later reused as kv
  short* kv    = Abf;                       // (32768x1024) bf16, written after Abf is dead
  short* ybf   = (short*)alloc(33554432);   // gemm1 out bf16; later reused as dots
  float* dots  = (float*)ybf;               // (32*1024*96) fp32 = 12.6MB
  short* inp   = (short*)alloc(33554432);   // LN'd input bf16
  short* Bt1   = (short*)alloc(1179648);    // w_in^T bf16 (512x1152)
  short* Btkv  = (short*)alloc(1048576);    // [wk|wv]^T bf16 (1024x512)
  short* wq_t  = (short*)alloc(524288);     // (512x512)
  short* wih_t = (short*)alloc(1572864);    // (1536x512)
  short* whh_t = (short*)alloc(1572864);    // (1536x512)
  short* w1_t  = (short*)alloc(2097152);    // (2048x512)
  short* w2_t  = (short*)alloc(2097152);    // (512x2048)
  short* sl1_t = (short*)alloc(262144);     // (256x512)
  float* slots = (float*)alloc(786432);
  short* slotsb= (short*)alloc(393216);
  short* sn    = (short*)alloc(393216);
  float* qb    = (float*)alloc(786432);
  short* updb  = (short*)alloc(393216);
  float* gx    = (float*)alloc(2359296);
  float* gh    = (float*)alloc(2359296);
  short* fln   = (short*)alloc(393216);
  short* f1    = (short*)alloc(1572864);
  float* hid   = (float*)alloc(393216);
  float* vsum  = (float*)alloc(65536);
  (void)ws_size; (void)in_sizes; (void)n_in; (void)out_size;

  k_convA<<<dim3(18432), dim3(256), 0, stream>>>(features, Abf, 4718592);
  k_transpose_bf<<<dim3(2304), dim3(256), 0, stream>>>(w_in, Bt1, 1152, 512);
  k_prep_kv<<<dim3(2048), dim3(256), 0, stream>>>(wk, wv, Btkv);
  k_transpose_bf<<<dim3(1024), dim3(256), 0, stream>>>(wq, wq_t, 512, 512);
  k_transpose_bf<<<dim3(3072), dim3(256), 0, stream>>>(gru_wih, wih_t, 512, 1536);
  k_transpose_bf<<<dim3(3072), dim3(256), 0, stream>>>(gru_whh, whh_t, 512, 1536);
  k_transpose_bf<<<dim3(4096), dim3(256), 0, stream>>>(ffn_w1, w1_t, 512, 2048);
  k_transpose_bf<<<dim3(4096), dim3(256), 0, stream>>>(ffn_w2, w2_t, 2048, 512);
  k_transpose_bf<<<dim3(512), dim3(256), 0, stream>>>(sel_w1, sl1_t, 512, 256);
  k_slots_init<<<dim3(768), dim3(256), 0, stream>>>(slot_mu, slot_ls, noise, slots, slotsb);

  // phase A: y = features @ w_in + b_in ; inp = LN2(LN1(y)) ; kv = inp @ [wk|wv]
  gemm_t<0,true,false,false><<<dim3(1024), dim3(256), 0, stream>>>(Abf, Bt1, b_in, fnull, fnull, ybf, 32768, 512, 1152);
  k_ln2<<<dim3(8192), dim3(256), 0, stream>>>(ybf, inp, ln1_g, ln1_b, ninput_g, ninput_b);
  gemm_t<0,true,false,false><<<dim3(2048), dim3(256), 0, stream>>>(inp, Btkv, fnull, fnull, fnull, kv, 32768, 1024, 512);
  k_vsum<<<dim3(4, 32), dim3(256), 0, stream>>>(kv, vsum);

  for (int it = 0; it < 3; ++it) {
    k_lnb<<<dim3(96), dim3(256), 0, stream>>>(slots, sn, nslots_g, nslots_b);
    gemm_t<0,false,false,false><<<dim3(12), dim3(256), 0, stream>>>(sn, wq_t, fnull, fnull, qb, snull, 384, 512, 512);
    k_dots<<<dim3(8, 8, 32), dim3(256), 0, stream>>>(qb, kv, dots);
    k_soft<<<dim3(4, 32), dim3(256), 0, stream>>>(dots, it == 2 ? out + 131328 : fnull);
    k_upd<<<dim3(8, 32), dim3(256), 0, stream>>>(dots, kv, vsum, updb);
    gemm_t<0,false,false,false><<<dim3(36), dim3(256), 0, stream>>>(updb, wih_t, gru_bih, fnull, gx, snull, 384, 1536, 512);
    gemm_t<0,false,false,false><<<dim3(36), dim3(256), 0, stream>>>(slotsb, whh_t, gru_bhh, fnull, gh, snull, 384, 1536, 512);
    k_gruact<<<dim3(768), dim3(256), 0, stream>>>(gx, gh, slots);
    k_lnb<<<dim3(96), dim3(256), 0, stream>>>(slots, fln, ffnln_g, ffnln_b);
    gemm_t<1,true,false,false><<<dim3(48), dim3(256), 0, stream>>>(fln, w1_t, ffn_b1, fnull, fnull, f1, 384, 2048, 512);
    gemm_t<0,false,true,true><<<dim3(12), dim3(256), 0, stream>>>(f1, w2_t, ffn_b2, slots, slots, slotsb, 384, 512, 2048);
  }

  gemm_t<2,false,false,false><<<dim3(6), dim3(256), 0, stream>>>(slotsb, sl1_t, sel_b1, fnull, hid, snull, 384, 256, 512);
  k_decide<<<dim3(32), dim3(64), 0, stream>>>(hid, sel_w2, sel_b2, slots, out);
}

// Round 4
// 851.722 us; speedup vs baseline: 1.8897x; 1.0026x over previous
//
#include <hip/hip_runtime.h>
#include <math.h>

typedef __attribute__((ext_vector_type(8))) short short8;
typedef __attribute__((ext_vector_type(4))) float f32x4;

typedef const __attribute__((address_space(1))) void gv_t;
typedef __attribute__((address_space(3))) void lv_t;

__device__ __forceinline__ float b2f(short u) {
  union { unsigned int i; float f; } c; c.i = ((unsigned int)(unsigned short)u) << 16; return c.f;
}
__device__ __forceinline__ short f2b(float f) {
  union { float f; unsigned int i; } c; c.f = f;
  unsigned int r = c.i + 0x7FFFu + ((c.i >> 16) & 1u);
  return (short)(r >> 16);
}
__device__ __forceinline__ short8 cvt8(float4 a, float4 b) {
  short8 r;
  r[0]=f2b(a.x); r[1]=f2b(a.y); r[2]=f2b(a.z); r[3]=f2b(a.w);
  r[4]=f2b(b.x); r[5]=f2b(b.y); r[6]=f2b(b.z); r[7]=f2b(b.w);
  return r;
}
__device__ __forceinline__ void glds(const short* g, short* l) {
  __builtin_amdgcn_global_load_lds((gv_t*)g, (lv_t*)l, 16, 0, 0);
}

// ---------------- mega prep: all weight transposes + GRU combine + slots init ----------------
// job ranges (blocks of 256): [0,2304) Bt1 | [2304,4352) Btkv | [4352,5376) wq_t |
// [5376,13568) wgru | [13568,17664) w1_t | [17664,21760) w2_t | [21760,22272) sl1_t |
// [22272,22280) gbias | [22280,23048) slots init

__global__ __launch_bounds__(256) void k_prep(
    const float* __restrict__ w_in, const float* __restrict__ wk, const float* __restrict__ wv,
    const float* __restrict__ wq, const float* __restrict__ wih, const float* __restrict__ whh,
    const float* __restrict__ bih, const float* __restrict__ bhh,
    const float* __restrict__ w1, const float* __restrict__ w2, const float* __restrict__ sl1,
    const float* __restrict__ mu, const float* __restrict__ lsig, const float* __restrict__ noise,
    short* __restrict__ Bt1, short* __restrict__ Btkv, short* __restrict__ wq_t,
    short* __restrict__ wgru, float* __restrict__ gbias,
    short* __restrict__ w1_t, short* __restrict__ w2_t, short* __restrict__ sl1_t,
    float* __restrict__ slots, short* __restrict__ gruA)
{
  int blk = blockIdx.x, t = threadIdx.x;
  if (blk < 2304) {                       // w_in (1152x512) -> Bt1 (512x1152)
    int idx = blk*256 + t;
    int kk = idx / 512, n = idx % 512;
    Bt1[(size_t)n*1152 + kk] = f2b(w_in[idx]);
  } else if (blk < 4352) {                // [wk|wv] -> Btkv (1024x512)
    int idx = (blk-2304)*256 + t;
    int kk = idx >> 10, n = idx & 1023;
    float v = (n < 512) ? wk[kk*512 + n] : wv[kk*512 + (n-512)];
    Btkv[(size_t)n*512 + kk] = f2b(v);
  } else if (blk < 5376) {                // wq (512x512) -> wq_t
    int idx = (blk-4352)*256 + t;
    int kk = idx >> 9, n = idx & 511;
    wq_t[n*512 + kk] = f2b(wq[idx]);
  } else if (blk < 13568) {               // combined GRU weight (2048 x 1024)
    int idx = (blk-5376)*256 + t;
    int n = idx >> 10, k = idx & 1023;
    int g = n >> 9, c = n & 511;
    float v;
    if (g == 0)      v = (k < 512) ? wih[k*1536 + c]        : whh[(k-512)*1536 + c];
    else if (g == 1) v = (k < 512) ? wih[k*1536 + 512 + c]  : whh[(k-512)*1536 + 512 + c];
    else if (g == 2) v = (k < 512) ? wih[k*1536 + 1024 + c] : 0.f;
    else             v = (k < 512) ? 0.f                    : whh[(k-512)*1536 + 1024 + c];
    wgru[(size_t)n*1024 + k] = f2b(v);
  } else if (blk < 17664) {               // ffn_w1 (512x2048) -> w1_t (2048x512)
    int idx = (blk-13568)*256 + t;
    int kk = idx >> 11, n = idx & 2047;
    w1_t[(size_t)n*512 + kk] = f2b(w1[idx]);
  } else if (blk < 21760) {               // ffn_w2 (2048x512) -> w2_t (512x2048)
    int idx = (blk-17664)*256 + t;
    int kk = idx >> 9, n = idx & 511;
    w2_t[(size_t)n*2048 + kk] = f2b(w2[idx]);
  } else if (blk < 22272) {               // sel_w1 (512x256) -> sl1_t (256x512)
    int idx = (blk-21760)*256 + t;
    int kk = idx >> 8, n = idx & 255;
    sl1_t[n*512 + kk] = f2b(sl1[idx]);
  } else if (blk < 22280) {               // combined GRU bias (2048)
    int n = (blk-22272)*256 + t;
    int g = n >> 9;
    float v;
    if (g <= 1)      v = bih[n] + bhh[n];
    else if (g == 2) v = bih[n];
    else             v = bhh[1024 + (n - 1536)];
    gbias[n] = v;
  } else {                                // slots init (fp32 + bf16 into gruA 2nd half)
    int idx = (blk-22280)*256 + t;
    int sd = idx % 6144;
    float v = mu[sd] + __expf(lsig[sd]) * noise[idx];
    slots[idx] = v;
    int row = idx >> 9, c = idx & 511;
    gruA[(size_t)row*1024 + 512 + c] = f2b(v);
  }
}

// ---------------- bf16 MFMA GEMM with 2-phase prefetch double-buffer ----------------
// C = act(A(MxK) @ Bt(NxK)^T + bias) (+res). 128x128 tile, BK=32, dbuf LDS (32KB),
// one barrier per K-step: stage(t+1, buf^1) || compute(t, buf). (T3-minimum, sec5.5)
// XCD-bijective block swizzle (T1/m204). LDS XOR swizzle kc ^ ((row>>1)&3):
// max 2-way bank alias on ds_read_b128 (free, m136). AF32: A is fp32, reg-staged
// (issue loads early, cvt+ds_write after compute = T14).
// ACT: 0 none, 1 gelu(exact), 2 relu.

template<int ACT, bool OUTBF, bool RES, bool DUAL, bool AF32>
__global__ __launch_bounds__(256) void gemm_t(
    const void* __restrict__ Av, const short* __restrict__ Bt,
    const float* __restrict__ bias, const float* __restrict__ res,
    float* __restrict__ Cf, short* __restrict__ Cb,
    int M, int N, int K, int lda, int ldf, int ldcb, int cboff)
{
  __shared__ short As[2][128*32];
  __shared__ short Bs[2][128*32];
  const short* Ab = (const short*)Av;
  const float* Af = (const float*)Av;
  const int t = threadIdx.x;
  const int lane = t & 63, wave = t >> 6;

  // T1 bijective XCD swizzle
  const int nwg = gridDim.x, gridX = N >> 7, orig = blockIdx.x;
  const int q = nwg >> 3, r = nwg & 7, xcd = orig & 7, base = orig >> 3;
  const int wgid = (xcd < r ? xcd*(q+1) : r*(q+1) + (xcd - r)*q) + base;
  const int bx = wgid % gridX, by = wgid / gridX;

  const int rowBase = by * 128, colBase = bx * 128;
  const int wm = (wave >> 1) * 64, wn = (wave & 1) * 64;
  const int fr = lane & 15, kc = lane >> 4;
  const int kswz8 = (kc ^ ((fr >> 1) & 3)) * 8;    // swizzled chunk offset (shorts)
  f32x4 acc[4][4] = {};

  // staging map: 512 chunks (16B) per matrix per step; thread t -> chunks t, 256+t
  const int c0 = t,      row0 = c0 >> 2, g0 = (((c0 & 3) ^ ((row0 >> 1) & 3))) * 8;
  const int c1 = 256+t,  row1 = c1 >> 2, g1 = (((c1 & 3) ^ ((row1 >> 1) & 3))) * 8;

  // prologue: stage kb=0 into buf 0
  if (AF32) {
    float4 p0 = *(const float4*)(Af + (size_t)(rowBase+row0)*lda + g0);
    float4 p1 = *(const float4*)(Af + (size_t)(rowBase+row0)*lda + g0 + 4);
    float4 p2 = *(const float4*)(Af + (size_t)(rowBase+row1)*lda + g1);
    float4 p3 = *(const float4*)(Af + (size_t)(rowBase+row1)*lda + g1 + 4);
    *(short8*)(As[0] + c0*8) = cvt8(p0, p1);
    *(short8*)(As[0] + c1*8) = cvt8(p2, p3);
  } else {
    glds(Ab + (size_t)(rowBase+row0)*lda + g0, As[0] + c0*8);
    glds(Ab + (size_t)(rowBase+row1)*lda + g1, As[0] + c1*8);
  }
  glds(Bt + (size_t)(colBase+row0)*K + g0, Bs[0] + c0*8);
  glds(Bt + (size_t)(colBase+row1)*K + g1, Bs[0] + c1*8);
  __syncthreads();

  int cur = 0;
  for (int kb = 0; kb < K; kb += 32) {
    const bool more = (kb + 32) < K;
    float4 p0, p1, p2, p3;
    if (more) {                           // issue prefetch into buf^1
      const int kn = kb + 32;
      if (AF32) {
        p0 = *(const float4*)(Af + (size_t)(rowBase+row0)*lda + kn + g0);
        p1 = *(const float4*)(Af + (size_t)(rowBase+row0)*lda + kn + g0 + 4);
        p2 = *(const float4*)(Af + (size_t)(rowBase+row1)*lda + kn + g1);
        p3 = *(const float4*)(Af + (size_t)(rowBase+row1)*lda + kn + g1 + 4);
      } else {
        glds(Ab + (size_t)(rowBase+row0)*lda + kn + g0, As[cur^1] + c0*8);
        glds(Ab + (size_t)(rowBase+row1)*lda + kn + g1, As[cur^1] + c1*8);
      }
      glds(Bt + (size_t)(colBase+row0)*K + kn + g0, Bs[cur^1] + c0*8);
      glds(Bt + (size_t)(colBase+row1)*K + kn + g1, Bs[cur^1] + c1*8);
    }
    // compute on buf cur
    short8 af[4], bf[4];
    #pragma unroll
    for (int m = 0; m < 4; ++m) af[m] = *(const short8*)(As[cur] + (wm + m*16 + fr)*32 + kswz8);
    #pragma unroll
    for (int n = 0; n < 4; ++n) bf[n] = *(const short8*)(Bs[cur] + (wn + n*16 + fr)*32 + kswz8);
    #pragma unroll
    for (int m = 0; m < 4; ++m)
      #pragma unroll
      for (int n = 0; n < 4; ++n)
        acc[m][n] = __builtin_amdgcn_mfma_f32_16x16x32_bf16(af[m], bf[n], acc[m][n], 0, 0, 0);
    if (more && AF32) {                   // write-late (T14)
      *(short8*)(As[cur^1] + c0*8) = cvt8(p0, p1);
      *(short8*)(As[cur^1] + c1*8) = cvt8(p2, p3);
    }
    __syncthreads();
    cur ^= 1;
  }

  const int cr = (lane >> 4) * 4, cc2 = lane & 15;
  #pragma unroll
  for (int m = 0; m < 4; ++m) {
    #pragma unroll
    for (int n = 0; n < 4; ++n) {
      int col = colBase + wn + n*16 + cc2;
      float bv = bias ? bias[col] : 0.f;
      #pragma unroll
      for (int j = 0; j < 4; ++j) {
        int row = rowBase + wm + m*16 + cr + j;
        float v = acc[m][n][j] + bv;
        if (ACT == 1) v = 0.5f*v*(1.f + erff(v*0.70710678118f));
        else if (ACT == 2) v = fmaxf(v, 0.f);
        size_t fidx = (size_t)row * ldf + col;
        if (RES) v += res[fidx];
        if (DUAL) { Cf[fidx] = v; Cb[(size_t)row*ldcb + cboff + col] = f2b(v); }
        else if (OUTBF) Cb[(size_t)row*ldcb + cboff + col] = f2b(v);
        else Cf[fidx] = v;
      }
    }
  }
}

// ---------------- double layernorm: inp = LN2(LN1(y)), bf16 in/out, wave per row ----------------

__global__ __launch_bounds__(256) void k_ln2(const short* __restrict__ y, short* __restrict__ inp,
    const float* __restrict__ g1, const float* __restrict__ b1,
    const float* __restrict__ g2, const float* __restrict__ b2)
{
  int t = threadIdx.x, lane = t & 63;
  int row = blockIdx.x * 4 + (t >> 6);
  const short8 raw = *(const short8*)(y + (size_t)row*512 + lane*8);
  float x[8];
  #pragma unroll
  for (int e = 0; e < 8; ++e) x[e] = b2f(raw[e]);
  float s = 0.f, ss = 0.f;
  #pragma unroll
  for (int e = 0; e < 8; ++e) { s += x[e]; ss += x[e]*x[e]; }
  #pragma unroll
  for (int m = 1; m < 64; m <<= 1) { s += __shfl_xor(s, m, 64); ss += __shfl_xor(ss, m, 64); }
  float mean = s * (1.f/512.f);
  float rs = rsqrtf(ss*(1.f/512.f) - mean*mean + 1e-5f);
  int c = lane * 8;
  #pragma unroll
  for (int e = 0; e < 8; ++e) x[e] = (x[e]-mean)*rs*g1[c+e] + b1[c+e];
  s = 0.f; ss = 0.f;
  #pragma unroll
  for (int e = 0; e < 8; ++e) { s += x[e]; ss += x[e]*x[e]; }
  #pragma unroll
  for (int m = 1; m < 64; m <<= 1) { s += __shfl_xor(s, m, 64); ss += __shfl_xor(ss, m, 64); }
  float mean2 = s * (1.f/512.f);
  float rs2 = rsqrtf(ss*(1.f/512.f) - mean2*mean2 + 1e-5f);
  short8 o;
  #pragma unroll
  for (int e = 0; e < 8; ++e) o[e] = f2b((x[e]-mean2)*rs2*g2[c+e] + b2[c+e]);
  *(short8*)(inp + (size_t)row*512 + lane*8) = o;
}

// ---------------- layernorm fp32 -> bf16, wave per row (512 cols) ----------------

__global__ __launch_bounds__(256) void k_lnb(const float* __restrict__ x, short* __restrict__ out,
    const float* __restrict__ g, const float* __restrict__ b)
{
  int t = threadIdx.x, lane = t & 63;
  int row = blockIdx.x * 4 + (t >> 6);
  const float* src = x + (size_t)row*512 + lane*8;
  float v[8];
  *(float4*)v = *(const float4*)src;
  *(float4*)(v+4) = *(const float4*)(src+4);
  float s = 0.f, ss = 0.f;
  #pragma unroll
  for (int e = 0; e < 8; ++e) { s += v[e]; ss += v[e]*v[e]; }
  #pragma unroll
  for (int m = 1; m < 64; m <<= 1) { s += __shfl_xor(s, m, 64); ss += __shfl_xor(ss, m, 64); }
  float mean = s * (1.f/512.f);
  float rs = rsqrtf(ss*(1.f/512.f) - mean*mean + 1e-5f);
  int c = lane * 8;
  short8 o;
  #pragma unroll
  for (int e = 0; e < 8; ++e) o[e] = f2b((v[e]-mean)*rs*g[c+e] + b[c+e]);
  *(short8*)(out + (size_t)row*512 + c) = o;
}

// ---------------- attention: dots = q . k * SCALE ; grid (jt=8, h=8, b=32) ----------------

__global__ __launch_bounds__(256) void k_dots(const float* __restrict__ q, const short* __restrict__ kv,
                                              float* __restrict__ dots)
{
  __shared__ __align__(16) float qs[12][64];
  __shared__ float ks[128][65];
  int t = threadIdx.x;
  int jt = blockIdx.x, h = blockIdx.y, b = blockIdx.z;
  if (t < 192) {
    int s = t >> 4, d4 = (t & 15) * 4;
    *(float4*)&qs[s][d4] = *(const float4*)(q + (size_t)(b*12+s)*512 + h*64 + d4);
  }
  #pragma unroll
  for (int i = 0; i < 4; ++i) {
    int c = i*256 + t;
    int jj = c >> 3, seg = (c & 7) * 8;
    short8 raw = *(const short8*)(kv + ((size_t)(b*1024 + jt*128 + jj))*1024 + h*64 + seg);
    #pragma unroll
    for (int e = 0; e < 8; ++e) ks[jj][seg+e] = b2f(raw[e]);
  }
  __syncthreads();
  int jj = t & 127, sg = t >> 7;
  float d6[6] = {};
  for (int d = 0; d < 64; ++d) {
    float kvv = ks[jj][d];
    #pragma unroll
    for (int i = 0; i < 6; ++i) d6[i] += qs[sg*6+i][d] * kvv;
  }
  float* o = dots + ((size_t)(b*1024 + jt*128 + jj))*96 + h;
  #pragma unroll
  for (int i = 0; i < 6; ++i) o[(sg*6+i)*8] = d6[i] * 0.125f;
}

// ---------------- softmax over the 96 (s,h) axis, in place; optional attn_out ----------------

__global__ __launch_bounds__(256) void k_soft(float* __restrict__ dots, float* __restrict__ aout)
{
  int t = threadIdx.x, b = blockIdx.y;
  int j = blockIdx.x * 256 + t;
  float* p = dots + ((size_t)(b*1024 + j)) * 96;
  float v[96];
  #pragma unroll
  for (int i = 0; i < 24; ++i) *(float4*)&v[i*4] = *(const float4*)(p + i*4);
  float mx = v[0];
  #pragma unroll
  for (int i = 1; i < 96; ++i) mx = fmaxf(mx, v[i]);
  float sum = 0.f;
  #pragma unroll
  for (int i = 0; i < 96; ++i) { v[i] = __expf(v[i]-mx); sum += v[i]; }
  float inv = 1.f/sum;
  #pragma unroll
  for (int i = 0; i < 96; ++i) v[i] *= inv;
  #pragma unroll
  for (int i = 0; i < 24; ++i) *(float4*)(p + i*4) = *(float4*)&v[i*4];
  if (aout) {
    #pragma unroll
    for (int s = 0; s < 8; ++s) {
      float m = 0.f;
      #pragma unroll
      for (int hh = 0; hh < 8; ++hh) m += v[s*8+hh];
      aout[(size_t)(b*8+s)*1024 + j] = m * 0.125f;
    }
  }
}

// ---------------- upd = sum_j v*attn / (den + 1e-8), bf16 into gruA 1st half ----------------
// grid (h=8, b=32). 1e-8 numerator terms dropped (relative error ~1e-6, negligible).

__global__ __launch_bounds__(256) void k_upd(const float* __restrict__ dots, const short* __restrict__ kv,
                                             short* __restrict__ gruA)
{
  __shared__ float atts[12][129];
  __shared__ float vs[128][65];
  __shared__ float den_s[12];
  int t = threadIdx.x;
  int h = blockIdx.x, b = blockIdx.y;
  int d = t & 63, sq = t >> 6;
  int jj2 = t & 127, sg = t >> 7;
  float acc[3] = {0.f, 0.f, 0.f};
  float myden = 0.f;
  for (int jt = 0; jt < 8; ++jt) {
    __syncthreads();
    const float* src = dots + ((size_t)(b*1024 + jt*128 + jj2))*96 + h;
    #pragma unroll
    for (int i = 0; i < 6; ++i) atts[sg*6+i][jj2] = src[(sg*6+i)*8];
    #pragma unroll
    for (int i = 0; i < 4; ++i) {
      int c = i*256 + t;
      int jj = c >> 3, seg = (c & 7)*8;
      short8 raw = *(const short8*)(kv + ((size_t)(b*1024 + jt*128 + jj))*1024 + 512 + h*64 + seg);
      #pragma unroll
      for (int e = 0; e < 8; ++e) vs[jj][seg+e] = b2f(raw[e]);
    }
    __syncthreads();
    for (int jj = 0; jj < 128; ++jj) {
      float vv = vs[jj][d];
      #pragma unroll
      for (int i = 0; i < 3; ++i) acc[i] += atts[sq + 4*i][jj] * vv;
    }
    if (t < 12) {
      float ls = 0.f;
      for (int jj = 0; jj < 128; ++jj) ls += atts[t][jj];
      myden += ls;
    }
  }
  __syncthreads();
  if (t < 12) den_s[t] = myden;
  __syncthreads();
  #pragma unroll
  for (int i = 0; i < 3; ++i) {
    int s = sq + 4*i;
    float r = acc[i] / (den_s[s] + 1e-8f);
    gruA[(size_t)(b*12+s)*1024 + h*64 + d] = f2b(r);
  }
}

// ---------------- GRU gate combine: gsum layout [r | z | xn | hn] (stride 2048) ----------------

__global__ __launch_bounds__(256) void k_gruact(const float* __restrict__ g, float* __restrict__ slots)
{
  int idx = blockIdx.x*256 + threadIdx.x; // 196608
  int row = idx >> 9, c = idx & 511;
  const float* gr = g + (size_t)row*2048;
  float r = 1.f/(1.f + __expf(-gr[c]));
  float z = 1.f/(1.f + __expf(-gr[512+c]));
  float n = tanhf(gr[1024+c] + r*gr[1536+c]);
  slots[idx] = (1.f - z)*n + z*slots[idx];
}

// ---------------- selector head: logits, decision logic, obj write ----------------

__global__ __launch_bounds__(64) void k_decide(const float* __restrict__ hid, const float* __restrict__ w2,
    const float* __restrict__ b2, const float* __restrict__ slots, float* __restrict__ out)
{
  __shared__ float lg[16];
  __shared__ float dec[8];
  int b = blockIdx.x, t = threadIdx.x;
  if (t < 16) {
    int s = t >> 1, cl = t & 1;
    const float* hr = hid + (size_t)(b*12+s)*256;
    float a = b2[cl];
    for (int k = 0; k < 256; ++k) a += hr[k] * w2[k*2+cl];
    lg[t] = a;
  }
  __syncthreads();
  if (t == 0) {
    float d0[8]; float tot = 0.f;
    #pragma unroll
    for (int s = 0; s < 8; ++s) { d0[s] = (lg[2*s+1] > lg[2*s]) ? 1.f : 0.f; tot += d0[s]; }
    float needed = fmaxf(0.f, 2.f - tot);
    float cum = 0.f;
    #pragma unroll
    for (int s = 0; s < 8; ++s) {
      cum += 1.f - d0[s];
      float add = (d0[s] == 0.f && cum <= needed) ? 1.f : 0.f;
      float dd = d0[s] + add;
      dec[s] = dd;
      out[131072 + b*8 + s] = dd;
    }
  }
  __syncthreads();
  for (int i = 0; i < 64; ++i) {
    int idx = i*64 + t;
    int s = idx >> 9, c = idx & 511;
    out[(size_t)(b*8+s)*512 + c] = slots[(size_t)(b*12+s)*512 + c] * dec[s];
  }
}

// ---------------- host ----------------

extern "C" void kernel_launch(void* const* d_in, const int* in_sizes, int n_in,
                              void* d_out, int out_size, void* d_ws, size_t ws_size,
                              hipStream_t stream) {
  const float* features = (const float*)d_in[0];
  const float* noise    = (const float*)d_in[1];
  const float* w_in     = (const float*)d_in[2];
  const float* b_in     = (const float*)d_in[3];
  const float* ln1_g    = (const float*)d_in[4];
  const float* ln1_b    = (const float*)d_in[5];
  const float* slot_mu  = (const float*)d_in[6];
  const float* slot_ls  = (const float*)d_in[7];
  const float* wq       = (const float*)d_in[8];
  const float* wk       = (const float*)d_in[9];
  const float* wv       = (const float*)d_in[10];
  const float* gru_wih  = (const float*)d_in[11];
  const float* gru_whh  = (const float*)d_in[12];
  const float* gru_bih  = (const float*)d_in[13];
  const float* gru_bhh  = (const float*)d_in[14];
  const float* nslots_g = (const float*)d_in[15];
  const float* nslots_b = (const float*)d_in[16];
  const float* ninput_g = (const float*)d_in[17];
  const float* ninput_b = (const float*)d_in[18];
  const float* ffnln_g  = (const float*)d_in[19];
  const float* ffnln_b  = (const float*)d_in[20];
  const float* ffn_w1   = (const float*)d_in[21];
  const float* ffn_b1   = (const float*)d_in[22];
  const float* ffn_w2   = (const float*)d_in[23];
  const float* ffn_b2   = (const float*)d_in[24];
  const float* sel_w1   = (const float*)d_in[25];
  const float* sel_b1   = (const float*)d_in[26];
  const float* sel_w2   = (const float*)d_in[27];
  const float* sel_b2   = (const float*)d_in[28];
  float* out = (float*)d_out;
  float* fnull = (float*)nullptr;
  short* snull = (short*)nullptr;

  char* w = (char*)d_ws;
  size_t off = 0;
  auto alloc = [&](size_t n) { char* p = w + off; off = (off + n + 255) & ~255ULL; return p; };
  short* kv    = (short*)alloc(67108864);   // (32768x1024) bf16
  short* ybf   = (short*)alloc(33554432);   // gemm1 out bf16; later reused as dots
  float* dots  = (float*)ybf;               // (32*1024*96) fp32 = 12.6MB
  short* inp   = (short*)alloc(33554432);   // LN'd input bf16
  short* Bt1   = (short*)alloc(1179648);    // w_in^T (512x1152)
  short* Btkv  = (short*)alloc(1048576);    // [wk|wv]^T (1024x512)
  short* wq_t  = (short*)alloc(524288);     // (512x512)
  short* wgru  = (short*)alloc(4194304);    // combined GRU weight (2048x1024)
  float* gbias = (float*)alloc(8192);       // combined GRU bias (2048)
  short* w1_t  = (short*)alloc(2097152);    // (2048x512)
  short* w2_t  = (short*)alloc(2097152);    // (512x2048)
  short* sl1_t = (short*)alloc(262144);     // (256x512)
  float* slots = (float*)alloc(786432);     // fp32 (384x512)
  short* gruA  = (short*)alloc(786432);     // bf16 [upd | slots] (384x1024)
  short* sn    = (short*)alloc(393216);
  float* qb    = (float*)alloc(786432);
  float* gsum  = (float*)alloc(3145728);    // (384x2048)
  short* fln   = (short*)alloc(393216);
  short* f1    = (short*)alloc(1572864);    // (384x2048) bf16
  float* hid   = (float*)alloc(393216);
  (void)ws_size; (void)in_sizes; (void)n_in; (void)out_size;

  k_prep<<<dim3(23048), dim3(256), 0, stream>>>(
      w_in, wk, wv, wq, gru_wih, gru_whh, gru_bih, gru_bhh,
      ffn_w1, ffn_w2, sel_w1, slot_mu, slot_ls, noise,
      Bt1, Btkv, wq_t, wgru, gbias, w1_t, w2_t, sl1_t, slots, gruA);

  // phase A: y = features @ w_in + b_in ; inp = LN2(LN1(y)) ; kv = inp @ [wk|wv]
  gemm_t<0,true,false,false,true><<<dim3(1024), dim3(256), 0, stream>>>(
      features, Bt1, b_in, fnull, fnull, ybf, 32768, 512, 1152, 1152, 0, 512, 0);
  k_ln2<<<dim3(8192), dim3(256), 0, stream>>>(ybf, inp, ln1_g, ln1_b, ninput_g, ninput_b);
  gemm_t<0,true,false,false,false><<<dim3(2048), dim3(256), 0, stream>>>(
      inp, Btkv, fnull, fnull, fnull, kv, 32768, 1024, 512, 512, 0, 1024, 0);

  for (int it = 0; it < 3; ++it) {
    k_lnb<<<dim3(96), dim3(256), 0, stream>>>(slots, sn, nslots_g, nslots_b);
    gemm_t<0,false,false,false,false><<<dim3(12), dim3(256), 0, stream>>>(
        sn, wq_t, fnull, fnull, qb, snull, 384, 512, 512, 512, 512, 0, 0);
    k_dots<<<dim3(8, 8, 32), dim3(256), 0, stream>>>(qb, kv, dots);
    k_soft<<<dim3(4, 32), dim3(256), 0, stream>>>(dots, it == 2 ? out + 131328 : fnull);
    k_upd<<<dim3(8, 32), dim3(256), 0, stream>>>(dots, kv, gruA);
    gemm_t<0,false,false,false,false><<<dim3(48), dim3(256), 0, stream>>>(
        gruA, wgru, gbias, fnull, gsum, snull, 384, 2048, 1024, 1024, 2048, 0, 0);
    k_gruact<<<dim3(768), dim3(256), 0, stream>>>(gsum, slots);
    k_lnb<<<dim3(96), dim3(256), 0, stream>>>(slots, fln, ffnln_g, ffnln_b);
    gemm_t<1,true,false,false,false><<<dim3(48), dim3(256), 0, stream>>>(
        fln, w1_t, ffn_b1, fnull, fnull, f1, 384, 2048, 512, 512, 0, 2048, 0);
    gemm_t<0,false,true,true,false><<<dim3(12), dim3(256), 0, stream>>>(
        f1, w2_t, ffn_b2, slots, slots, gruA, 384, 512, 2048, 2048, 512, 1024, 512);
  }

  gemm_t<2,false,false,false,false><<<dim3(6), dim3(256), 0, stream>>>(
      gruA + 512, sl1_t, sel_b1, fnull, hid, snull, 384, 256, 512, 1024, 256, 0, 0);
  k_decide<<<dim3(32), dim3(64), 0, stream>>>(hid, sel_w2, sel_b2, slots, out);
}

// Round 5
// 622.009 us; speedup vs baseline: 2.5876x; 1.3693x over previous
//
#include <hip/hip_runtime.h>
#include <math.h>

typedef __attribute__((ext_vector_type(8))) short short8;
typedef __attribute__((ext_vector_type(4))) float f32x4;

typedef const __attribute__((address_space(1))) void gv_t;
typedef __attribute__((address_space(3))) void lv_t;

__device__ __forceinline__ float b2f(short u) {
  union { unsigned int i; float f; } c; c.i = ((unsigned int)(unsigned short)u) << 16; return c.f;
}
__device__ __forceinline__ short f2b(float f) {
  union { float f; unsigned int i; } c; c.f = f;
  unsigned int r = c.i + 0x7FFFu + ((c.i >> 16) & 1u);
  return (short)(r >> 16);
}
__device__ __forceinline__ void glds(const short* g, short* l) {
  __builtin_amdgcn_global_load_lds((gv_t*)g, (lv_t*)l, 16, 0, 0);
}

// ---------------- prep kernels ----------------

__global__ __launch_bounds__(256) void k_convA(const float* __restrict__ in, short* __restrict__ out, int n8) {
  int idx = blockIdx.x * 256 + threadIdx.x;
  if (idx >= n8) return;
  const float4* p = (const float4*)(in + (size_t)idx * 8);
  float4 a = p[0], b = p[1];
  short8 r;
  r[0]=f2b(a.x); r[1]=f2b(a.y); r[2]=f2b(a.z); r[3]=f2b(a.w);
  r[4]=f2b(b.x); r[5]=f2b(b.y); r[6]=f2b(b.z); r[7]=f2b(b.w);
  *(short8*)(out + (size_t)idx*8) = r;
}

// mega prep: all weight transposes + GRU combine + slots init
// ranges (blocks of 256): [0,2304) Bt1 | [2304,4352) Btkv | [4352,5376) wq_t |
// [5376,13568) wgru | [13568,17664) w1_t | [17664,21760) w2_t | [21760,22272) sl1_t |
// [22272,22280) gbias | [22280,23048) slots init

__global__ __launch_bounds__(256) void k_prep(
    const float* __restrict__ w_in, const float* __restrict__ wk, const float* __restrict__ wv,
    const float* __restrict__ wq, const float* __restrict__ wih, const float* __restrict__ whh,
    const float* __restrict__ bih, const float* __restrict__ bhh,
    const float* __restrict__ w1, const float* __restrict__ w2, const float* __restrict__ sl1,
    const float* __restrict__ mu, const float* __restrict__ lsig, const float* __restrict__ noise,
    short* __restrict__ Bt1, short* __restrict__ Btkv, short* __restrict__ wq_t,
    short* __restrict__ wgru, float* __restrict__ gbias,
    short* __restrict__ w1_t, short* __restrict__ w2_t, short* __restrict__ sl1_t,
    float* __restrict__ slots, short* __restrict__ gruA)
{
  int blk = blockIdx.x, t = threadIdx.x;
  if (blk < 2304) {                       // w_in (1152x512) -> Bt1 (512x1152)
    int idx = blk*256 + t;
    int kk = idx / 512, n = idx % 512;
    Bt1[(size_t)n*1152 + kk] = f2b(w_in[idx]);
  } else if (blk < 4352) {                // [wk|wv] -> Btkv (1024x512)
    int idx = (blk-2304)*256 + t;
    int kk = idx >> 10, n = idx & 1023;
    float v = (n < 512) ? wk[kk*512 + n] : wv[kk*512 + (n-512)];
    Btkv[(size_t)n*512 + kk] = f2b(v);
  } else if (blk < 5376) {                // wq (512x512) -> wq_t
    int idx = (blk-4352)*256 + t;
    int kk = idx >> 9, n = idx & 511;
    wq_t[n*512 + kk] = f2b(wq[idx]);
  } else if (blk < 13568) {               // combined GRU weight (2048 x 1024): [r|z|xn|hn]
    int idx = (blk-5376)*256 + t;
    int n = idx >> 10, k = idx & 1023;
    int g = n >> 9, c = n & 511;
    float v;
    if (g == 0)      v = (k < 512) ? wih[k*1536 + c]        : whh[(k-512)*1536 + c];
    else if (g == 1) v = (k < 512) ? wih[k*1536 + 512 + c]  : whh[(k-512)*1536 + 512 + c];
    else if (g == 2) v = (k < 512) ? wih[k*1536 + 1024 + c] : 0.f;
    else             v = (k < 512) ? 0.f                    : whh[(k-512)*1536 + 1024 + c];
    wgru[(size_t)n*1024 + k] = f2b(v);
  } else if (blk < 17664) {               // ffn_w1 (512x2048) -> w1_t (2048x512)
    int idx = (blk-13568)*256 + t;
    int kk = idx >> 11, n = idx & 2047;
    w1_t[(size_t)n*512 + kk] = f2b(w1[idx]);
  } else if (blk < 21760) {               // ffn_w2 (2048x512) -> w2_t (512x2048)
    int idx = (blk-17664)*256 + t;
    int kk = idx >> 9, n = idx & 511;
    w2_t[(size_t)n*2048 + kk] = f2b(w2[idx]);
  } else if (blk < 22272) {               // sel_w1 (512x256) -> sl1_t (256x512)
    int idx = (blk-21760)*256 + t;
    int kk = idx >> 8, n = idx & 255;
    sl1_t[n*512 + kk] = f2b(sl1[idx]);
  } else if (blk < 22280) {               // combined GRU bias (2048)
    int n = (blk-22272)*256 + t;
    int g = n >> 9;
    float v;
    if (g <= 1)      v = bih[n] + bhh[n];
    else if (g == 2) v = bih[n];
    else             v = bhh[1024 + (n - 1536)];
    gbias[n] = v;
  } else {                                // slots init (fp32 + bf16 into gruA 2nd half)
    int idx = (blk-22280)*256 + t;
    int sd = idx % 6144;
    float v = mu[sd] + __expf(lsig[sd]) * noise[idx];
    slots[idx] = v;
    int row = idx >> 9, c = idx & 511;
    gruA[(size_t)row*1024 + 512 + c] = f2b(v);
  }
}

// ---------------- bf16 MFMA GEMM (round-3 structure + optional split-K) ----------------
// C = act(A(Mx?) @ Bt^T + bias). 128x128 tile, BK=64, single-buffer 32KB LDS,
// 2 barriers per K-step (proven best measured structure). T1 bijective XCD swizzle
// on blockIdx.x. LDS XOR swizzle (chunk ^ (row&7)) via pre-swizzled global source
// + swizzled fragment read (rule #21 both-sides) -> 2-way max bank alias (free).
// SPLITK: blockIdx.y = K-slice; raw fp32 partial to Cf + y*skstride (no bias/act).

template<int ACT, bool OUTBF, bool SPLITK>
__global__ __launch_bounds__(256) void gemm_t(
    const short* __restrict__ A, const short* __restrict__ Bt,
    const float* __restrict__ bias,
    float* __restrict__ Cf, short* __restrict__ Cb,
    int N, int Kp, int lda, int ldb, int ldf, int ldcb, int cboff, int skstride)
{
  __shared__ short As[128*64];
  __shared__ short Bs[128*64];
  const int t = threadIdx.x;
  const int lane = t & 63, wave = t >> 6;

  const int nwg = gridDim.x, gridX = N >> 7, orig = blockIdx.x;
  const int q = nwg >> 3, r = nwg & 7, xcd = orig & 7, base = orig >> 3;
  const int wgid = (xcd < r ? xcd*(q+1) : r*(q+1) + (xcd - r)*q) + base;
  const int bx = wgid % gridX, by = wgid / gridX;

  const int rowBase = by * 128, colBase = bx * 128;
  const size_t koff = (size_t)blockIdx.y * Kp;
  const int wm = (wave >> 1) * 64, wn = (wave & 1) * 64;
  const int fr = lane & 15, kcf = lane >> 4;
  f32x4 acc[4][4] = {};

  int srow[4], scol[4];
  #pragma unroll
  for (int i = 0; i < 4; ++i) {
    int c = i*256 + t;
    srow[i] = c >> 3;
    scol[i] = ((c & 7) ^ (srow[i] & 7)) * 8;
  }

  for (int kb = 0; kb < Kp; kb += 64) {
    __syncthreads();
    #pragma unroll
    for (int i = 0; i < 4; ++i) {
      int c = i*256 + t;
      glds(A + (size_t)(rowBase + srow[i])*lda + koff + kb + scol[i], As + c*8);
      glds(Bt + (size_t)(colBase + srow[i])*ldb + koff + kb + scol[i], Bs + c*8);
    }
    __syncthreads();
    #pragma unroll
    for (int ks = 0; ks < 2; ++ks) {
      short8 af[4], bf[4];
      #pragma unroll
      for (int m = 0; m < 4; ++m) {
        int row = wm + m*16 + fr;
        int kc = ks*4 + kcf;
        af[m] = *(const short8*)(As + row*64 + (kc ^ (row & 7))*8);
      }
      #pragma unroll
      for (int n = 0; n < 4; ++n) {
        int row = wn + n*16 + fr;
        int kc = ks*4 + kcf;
        bf[n] = *(const short8*)(Bs + row*64 + (kc ^ (row & 7))*8);
      }
      #pragma unroll
      for (int m = 0; m < 4; ++m)
        #pragma unroll
        for (int n = 0; n < 4; ++n)
          acc[m][n] = __builtin_amdgcn_mfma_f32_16x16x32_bf16(af[m], bf[n], acc[m][n], 0, 0, 0);
    }
  }

  const int cr = (lane >> 4) * 4, cc2 = lane & 15;
  if (SPLITK) {
    float* dst = Cf + (size_t)blockIdx.y * skstride;
    #pragma unroll
    for (int m = 0; m < 4; ++m)
      #pragma unroll
      for (int n = 0; n < 4; ++n) {
        int col = colBase + wn + n*16 + cc2;
        #pragma unroll
        for (int j = 0; j < 4; ++j) {
          int row = rowBase + wm + m*16 + cr + j;
          dst[(size_t)row * ldf + col] = acc[m][n][j];
        }
      }
  } else {
    #pragma unroll
    for (int m = 0; m < 4; ++m)
      #pragma unroll
      for (int n = 0; n < 4; ++n) {
        int col = colBase + wn + n*16 + cc2;
        float bv = bias ? bias[col] : 0.f;
        #pragma unroll
        for (int j = 0; j < 4; ++j) {
          int row = rowBase + wm + m*16 + cr + j;
          float v = acc[m][n][j] + bv;
          if (ACT == 1) v = 0.5f*v*(1.f + erff(v*0.70710678118f));
          else if (ACT == 2) v = fmaxf(v, 0.f);
          if (OUTBF) Cb[(size_t)row*ldcb + cboff + col] = f2b(v);
          else Cf[(size_t)row*ldf + col] = v;
        }
      }
  }
}

// ---------------- split-K reduce kernels ----------------

// qb = sum of 4 partials (384x512), no bias
__global__ __launch_bounds__(256) void k_qred(const float* __restrict__ p, float* __restrict__ qb) {
  int i = blockIdx.x*256 + threadIdx.x; // 24576
  const float4* p4 = (const float4*)p;
  float4 a = p4[(size_t)i*2], b = p4[(size_t)i*2+1];
  #pragma unroll
  for (int s = 1; s < 4; ++s) {
    float4 x = p4[(size_t)s*49152 + i*2], y = p4[(size_t)s*49152 + i*2+1];
    a.x+=x.x; a.y+=x.y; a.z+=x.z; a.w+=x.w;
    b.x+=y.x; b.y+=y.y; b.z+=y.z; b.w+=y.w;
  }
  ((float4*)qb)[(size_t)i*2] = a; ((float4*)qb)[(size_t)i*2+1] = b;
}

// GRU: sum 4 partials (384x2048 = [r|z|xn|hn]) + bias, combine, update slots fp32
__global__ __launch_bounds__(256) void k_gruact_sk(const float* __restrict__ p, const float* __restrict__ gbias,
                                                   float* __restrict__ slots)
{
  int idx = blockIdx.x*256 + threadIdx.x; // 196608
  int row = idx >> 9, c = idx & 511;
  const float* base = p + (size_t)row*2048 + c;
  float g0=gbias[c], g1=gbias[512+c], g2=gbias[1024+c], g3=gbias[1536+c];
  #pragma unroll
  for (int s = 0; s < 4; ++s) {
    const float* qq = base + (size_t)s*786432;
    g0 += qq[0]; g1 += qq[512]; g2 += qq[1024]; g3 += qq[1536];
  }
  float r = 1.f/(1.f+__expf(-g0));
  float z = 1.f/(1.f+__expf(-g1));
  float n = tanhf(g2 + r*g3);
  slots[idx] = (1.f-z)*n + z*slots[idx];
}

// ffn1: sum 2 partials (384x2048) + bias, gelu, bf16 out
__global__ __launch_bounds__(256) void k_ffn1red(const float* __restrict__ p, const float* __restrict__ b1,
                                                 short* __restrict__ f1) {
  int i = blockIdx.x*256 + threadIdx.x; // 98304
  int col = (i*8) & 2047;
  float v[8], w[8];
  *(float4*)v = *(const float4*)(p + (size_t)i*8);
  *(float4*)(v+4) = *(const float4*)(p + (size_t)i*8 + 4);
  const float* p2 = p + 786432;
  *(float4*)w = *(const float4*)(p2 + (size_t)i*8);
  *(float4*)(w+4) = *(const float4*)(p2 + (size_t)i*8 + 4);
  short8 o;
  #pragma unroll
  for (int e = 0; e < 8; ++e) {
    float x = v[e] + w[e] + b1[col + e];
    x = 0.5f*x*(1.f + erff(x*0.70710678118f));
    o[e] = f2b(x);
  }
  *(short8*)(f1 + (size_t)i*8) = o;
}

// ffn2: sum 8 partials (384x512) + bias + residual -> slots fp32 AND gruA bf16 @512
__global__ __launch_bounds__(256) void k_ffn2red(const float* __restrict__ p, const float* __restrict__ b2,
                                                 float* __restrict__ slots, short* __restrict__ gruA) {
  int i = blockIdx.x*256 + threadIdx.x; // 24576
  int base = i*8;
  int row = base >> 9, c = base & 511;
  float v[8] = {0.f,0.f,0.f,0.f,0.f,0.f,0.f,0.f};
  #pragma unroll
  for (int s = 0; s < 8; ++s) {
    const float* qq = p + (size_t)s*196608 + base;
    float4 a = *(const float4*)qq, b = *(const float4*)(qq+4);
    v[0]+=a.x; v[1]+=a.y; v[2]+=a.z; v[3]+=a.w;
    v[4]+=b.x; v[5]+=b.y; v[6]+=b.z; v[7]+=b.w;
  }
  float sl[8];
  *(float4*)sl = *(const float4*)(slots + base);
  *(float4*)(sl+4) = *(const float4*)(slots + base + 4);
  short8 o;
  #pragma unroll
  for (int e = 0; e < 8; ++e) {
    float ns = sl[e] + v[e] + b2[c+e];
    sl[e] = ns;
    o[e] = f2b(ns);
  }
  *(float4*)(slots + base) = *(float4*)sl;
  *(float4*)(slots + base + 4) = *(float4*)(sl+4);
  *(short8*)(gruA + (size_t)row*1024 + 512 + c) = o;
}

// ---------------- double layernorm: inp = LN2(LN1(y)), bf16 in/out, wave per row ----------------

__global__ __launch_bounds__(256) void k_ln2(const short* __restrict__ y, short* __restrict__ inp,
    const float* __restrict__ g1, const float* __restrict__ b1,
    const float* __restrict__ g2, const float* __restrict__ b2)
{
  int t = threadIdx.x, lane = t & 63;
  int row = blockIdx.x * 4 + (t >> 6);
  const short8 raw = *(const short8*)(y + (size_t)row*512 + lane*8);
  float x[8];
  #pragma unroll
  for (int e = 0; e < 8; ++e) x[e] = b2f(raw[e]);
  float s = 0.f, ss = 0.f;
  #pragma unroll
  for (int e = 0; e < 8; ++e) { s += x[e]; ss += x[e]*x[e]; }
  #pragma unroll
  for (int m = 1; m < 64; m <<= 1) { s += __shfl_xor(s, m, 64); ss += __shfl_xor(ss, m, 64); }
  float mean = s * (1.f/512.f);
  float rs = rsqrtf(ss*(1.f/512.f) - mean*mean + 1e-5f);
  int c = lane * 8;
  #pragma unroll
  for (int e = 0; e < 8; ++e) x[e] = (x[e]-mean)*rs*g1[c+e] + b1[c+e];
  s = 0.f; ss = 0.f;
  #pragma unroll
  for (int e = 0; e < 8; ++e) { s += x[e]; ss += x[e]*x[e]; }
  #pragma unroll
  for (int m = 1; m < 64; m <<= 1) { s += __shfl_xor(s, m, 64); ss += __shfl_xor(ss, m, 64); }
  float mean2 = s * (1.f/512.f);
  float rs2 = rsqrtf(ss*(1.f/512.f) - mean2*mean2 + 1e-5f);
  short8 o;
  #pragma unroll
  for (int e = 0; e < 8; ++e) o[e] = f2b((x[e]-mean2)*rs2*g2[c+e] + b2[c+e]);
  *(short8*)(inp + (size_t)row*512 + lane*8) = o;
}

// ---------------- layernorm fp32 -> bf16, wave per row (512 cols) ----------------

__global__ __launch_bounds__(256) void k_lnb(const float* __restrict__ x, short* __restrict__ out,
    const float* __restrict__ g, const float* __restrict__ b)
{
  int t = threadIdx.x, lane = t & 63;
  int row = blockIdx.x * 4 + (t >> 6);
  const float* src = x + (size_t)row*512 + lane*8;
  float v[8];
  *(float4*)v = *(const float4*)src;
  *(float4*)(v+4) = *(const float4*)(src+4);
  float s = 0.f, ss = 0.f;
  #pragma unroll
  for (int e = 0; e < 8; ++e) { s += v[e]; ss += v[e]*v[e]; }
  #pragma unroll
  for (int m = 1; m < 64; m <<= 1) { s += __shfl_xor(s, m, 64); ss += __shfl_xor(ss, m, 64); }
  float mean = s * (1.f/512.f);
  float rs = rsqrtf(ss*(1.f/512.f) - mean*mean + 1e-5f);
  int c = lane * 8;
  short8 o;
  #pragma unroll
  for (int e = 0; e < 8; ++e) o[e] = f2b((v[e]-mean)*rs*g[c+e] + b[c+e]);
  *(short8*)(out + (size_t)row*512 + c) = o;
}

// ---------------- attention: dots = q . k * SCALE ; grid (jt=8, h=8, b=32) ----------------

__global__ __launch_bounds__(256) void k_dots(const float* __restrict__ q, const short* __restrict__ kv,
                                              float* __restrict__ dots)
{
  __shared__ __align__(16) float qs[12][64];
  __shared__ float ks[128][65];
  int t = threadIdx.x;
  int jt = blockIdx.x, h = blockIdx.y, b = blockIdx.z;
  if (t < 192) {
    int s = t >> 4, d4 = (t & 15) * 4;
    *(float4*)&qs[s][d4] = *(const float4*)(q + (size_t)(b*12+s)*512 + h*64 + d4);
  }
  #pragma unroll
  for (int i = 0; i < 4; ++i) {
    int c = i*256 + t;
    int jj = c >> 3, seg = (c & 7) * 8;
    short8 raw = *(const short8*)(kv + ((size_t)(b*1024 + jt*128 + jj))*1024 + h*64 + seg);
    #pragma unroll
    for (int e = 0; e < 8; ++e) ks[jj][seg+e] = b2f(raw[e]);
  }
  __syncthreads();
  int jj = t & 127, sg = t >> 7;
  float d6[6] = {};
  for (int d = 0; d < 64; ++d) {
    float kvv = ks[jj][d];
    #pragma unroll
    for (int i = 0; i < 6; ++i) d6[i] += qs[sg*6+i][d] * kvv;
  }
  float* o = dots + ((size_t)(b*1024 + jt*128 + jj))*96 + h;
  #pragma unroll
  for (int i = 0; i < 6; ++i) o[(sg*6+i)*8] = d6[i] * 0.125f;
}

// ---------------- softmax over the 96 (s,h) axis, in place; optional attn_out ----------------

__global__ __launch_bounds__(256) void k_soft(float* __restrict__ dots, float* __restrict__ aout)
{
  int t = threadIdx.x, b = blockIdx.y;
  int j = blockIdx.x * 256 + t;
  float* p = dots + ((size_t)(b*1024 + j)) * 96;
  float v[96];
  #pragma unroll
  for (int i = 0; i < 24; ++i) *(float4*)&v[i*4] = *(const float4*)(p + i*4);
  float mx = v[0];
  #pragma unroll
  for (int i = 1; i < 96; ++i) mx = fmaxf(mx, v[i]);
  float sum = 0.f;
  #pragma unroll
  for (int i = 0; i < 96; ++i) { v[i] = __expf(v[i]-mx); sum += v[i]; }
  float inv = 1.f/sum;
  #pragma unroll
  for (int i = 0; i < 96; ++i) v[i] *= inv;
  #pragma unroll
  for (int i = 0; i < 24; ++i) *(float4*)(p + i*4) = *(float4*)&v[i*4];
  if (aout) {
    #pragma unroll
    for (int s = 0; s < 8; ++s) {
      float m = 0.f;
      #pragma unroll
      for (int hh = 0; hh < 8; ++hh) m += v[s*8+hh];
      aout[(size_t)(b*8+s)*1024 + j] = m * 0.125f;
    }
  }
}

// ---------------- upd = sum_j v*attn / (den + 1e-8), bf16 into gruA 1st half ----------------
// grid (h=8, b=32)

__global__ __launch_bounds__(256) void k_upd(const float* __restrict__ dots, const short* __restrict__ kv,
                                             short* __restrict__ gruA)
{
  __shared__ float atts[12][129];
  __shared__ float vs[128][65];
  __shared__ float den_s[12];
  int t = threadIdx.x;
  int h = blockIdx.x, b = blockIdx.y;
  int d = t & 63, sq = t >> 6;
  int jj2 = t & 127, sg = t >> 7;
  float acc[3] = {0.f, 0.f, 0.f};
  float myden = 0.f;
  for (int jt = 0; jt < 8; ++jt) {
    __syncthreads();
    const float* src = dots + ((size_t)(b*1024 + jt*128 + jj2))*96 + h;
    #pragma unroll
    for (int i = 0; i < 6; ++i) atts[sg*6+i][jj2] = src[(sg*6+i)*8];
    #pragma unroll
    for (int i = 0; i < 4; ++i) {
      int c = i*256 + t;
      int jj = c >> 3, seg = (c & 7)*8;
      short8 raw = *(const short8*)(kv + ((size_t)(b*1024 + jt*128 + jj))*1024 + 512 + h*64 + seg);
      #pragma unroll
      for (int e = 0; e < 8; ++e) vs[jj][seg+e] = b2f(raw[e]);
    }
    __syncthreads();
    for (int jj = 0; jj < 128; ++jj) {
      float vv = vs[jj][d];
      #pragma unroll
      for (int i = 0; i < 3; ++i) acc[i] += atts[sq + 4*i][jj] * vv;
    }
    if (t < 12) {
      float ls = 0.f;
      for (int jj = 0; jj < 128; ++jj) ls += atts[t][jj];
      myden += ls;
    }
  }
  __syncthreads();
  if (t < 12) den_s[t] = myden;
  __syncthreads();
  #pragma unroll
  for (int i = 0; i < 3; ++i) {
    int s = sq + 4*i;
    float r = acc[i] / (den_s[s] + 1e-8f);
    gruA[(size_t)(b*12+s)*1024 + h*64 + d] = f2b(r);
  }
}

// ---------------- selector head: logits, decision logic, obj write ----------------

__global__ __launch_bounds__(64) void k_decide(const float* __restrict__ hid, const float* __restrict__ w2,
    const float* __restrict__ b2, const float* __restrict__ slots, float* __restrict__ out)
{
  __shared__ float lg[16];
  __shared__ float dec[8];
  int b = blockIdx.x, t = threadIdx.x;
  if (t < 16) {
    int s = t >> 1, cl = t & 1;
    const float* hr = hid + (size_t)(b*12+s)*256;
    float a = b2[cl];
    for (int k = 0; k < 256; ++k) a += hr[k] * w2[k*2+cl];
    lg[t] = a;
  }
  __syncthreads();
  if (t == 0) {
    float d0[8]; float tot = 0.f;
    #pragma unroll
    for (int s = 0; s < 8; ++s) { d0[s] = (lg[2*s+1] > lg[2*s]) ? 1.f : 0.f; tot += d0[s]; }
    float needed = fmaxf(0.f, 2.f - tot);
    float cum = 0.f;
    #pragma unroll
    for (int s = 0; s < 8; ++s) {
      cum += 1.f - d0[s];
      float add = (d0[s] == 0.f && cum <= needed) ? 1.f : 0.f;
      float dd = d0[s] + add;
      dec[s] = dd;
      out[131072 + b*8 + s] = dd;
    }
  }
  __syncthreads();
  for (int i = 0; i < 64; ++i) {
    int idx = i*64 + t;
    int s = idx >> 9, c = idx & 511;
    out[(size_t)(b*8+s)*512 + c] = slots[(size_t)(b*12+s)*512 + c] * dec[s];
  }
}

// ---------------- host ----------------

extern "C" void kernel_launch(void* const* d_in, const int* in_sizes, int n_in,
                              void* d_out, int out_size, void* d_ws, size_t ws_size,
                              hipStream_t stream) {
  const float* features = (const float*)d_in[0];
  const float* noise    = (const float*)d_in[1];
  const float* w_in     = (const float*)d_in[2];
  const float* b_in     = (const float*)d_in[3];
  const float* ln1_g    = (const float*)d_in[4];
  const float* ln1_b    = (const float*)d_in[5];
  const float* slot_mu  = (const float*)d_in[6];
  const float* slot_ls  = (const float*)d_in[7];
  const float* wq       = (const float*)d_in[8];
  const float* wk       = (const float*)d_in[9];
  const float* wv       = (const float*)d_in[10];
  const float* gru_wih  = (const float*)d_in[11];
  const float* gru_whh  = (const float*)d_in[12];
  const float* gru_bih  = (const float*)d_in[13];
  const float* gru_bhh  = (const float*)d_in[14];
  const float* nslots_g = (const float*)d_in[15];
  const float* nslots_b = (const float*)d_in[16];
  const float* ninput_g = (const float*)d_in[17];
  const float* ninput_b = (const float*)d_in[18];
  const float* ffnln_g  = (const float*)d_in[19];
  const float* ffnln_b  = (const float*)d_in[20];
  const float* ffn_w1   = (const float*)d_in[21];
  const float* ffn_b1   = (const float*)d_in[22];
  const float* ffn_w2   = (const float*)d_in[23];
  const float* ffn_b2   = (const float*)d_in[24];
  const float* sel_w1   = (const float*)d_in[25];
  const float* sel_b1   = (const float*)d_in[26];
  const float* sel_w2   = (const float*)d_in[27];
  const float* sel_b2   = (const float*)d_in[28];
  float* out = (float*)d_out;
  float* fnull = (float*)nullptr;
  short* snull = (short*)nullptr;

  char* w = (char*)d_ws;
  size_t off = 0;
  auto alloc = [&](size_t n) { char* p = w + off; off = (off + n + 255) & ~255ULL; return p; };
  short* Abf   = (short*)alloc(75497472);   // features bf16 (32768x1152); reused as kv
  short* kv    = Abf;                       // (32768x1024) bf16, written after Abf dead
  short* ybf   = (short*)alloc(33554432);   // gemm1 out bf16; reused as dots
  float* dots  = (float*)ybf;               // (32*1024*96) fp32
  short* inp   = (short*)alloc(33554432);   // LN'd input bf16
  short* Bt1   = (short*)alloc(1179648);    // w_in^T (512x1152)
  short* Btkv  = (short*)alloc(1048576);    // [wk|wv]^T (1024x512)
  short* wq_t  = (short*)alloc(524288);     // (512x512)
  short* wgru  = (short*)alloc(4194304);    // combined GRU weight (2048x1024)
  float* gbias = (float*)alloc(8192);       // combined GRU bias (2048)
  short* w1_t  = (short*)alloc(2097152);    // (2048x512)
  short* w2_t  = (short*)alloc(2097152);    // (512x2048)
  short* sl1_t = (short*)alloc(262144);     // (256x512)
  float* slots = (float*)alloc(786432);     // fp32 (384x512)
  short* gruA  = (short*)alloc(786432);     // bf16 [upd | slots] (384x1024)
  short* sn    = (short*)alloc(393216);
  float* qb    = (float*)alloc(786432);
  float* parts = (float*)alloc(12582912);   // split-K partials (max 4 x 384x2048 fp32)
  short* fln   = (short*)alloc(393216);
  short* f1    = (short*)alloc(1572864);    // (384x2048) bf16
  float* hid   = (float*)alloc(393216);
  (void)ws_size; (void)in_sizes; (void)n_in; (void)out_size;

  k_convA<<<dim3(18432), dim3(256), 0, stream>>>(features, Abf, 4718592);
  k_prep<<<dim3(23048), dim3(256), 0, stream>>>(
      w_in, wk, wv, wq, gru_wih, gru_whh, gru_bih, gru_bhh,
      ffn_w1, ffn_w2, sel_w1, slot_mu, slot_ls, noise,
      Bt1, Btkv, wq_t, wgru, gbias, w1_t, w2_t, sl1_t, slots, gruA);

  // phase A: y = features @ w_in + b_in ; inp = LN2(LN1(y)) ; kv = inp @ [wk|wv]
  gemm_t<0,true,false><<<dim3(1024), dim3(256), 0, stream>>>(
      Abf, Bt1, b_in, fnull, ybf, 512, 1152, 1152, 1152, 512, 512, 0, 0);
  k_ln2<<<dim3(8192), dim3(256), 0, stream>>>(ybf, inp, ln1_g, ln1_b, ninput_g, ninput_b);
  gemm_t<0,true,false><<<dim3(2048), dim3(256), 0, stream>>>(
      inp, Btkv, fnull, fnull, kv, 1024, 512, 512, 512, 1024, 1024, 0, 0);

  for (int it = 0; it < 3; ++it) {
    k_lnb<<<dim3(96), dim3(256), 0, stream>>>(slots, sn, nslots_g, nslots_b);
    gemm_t<0,false,true><<<dim3(12, 4), dim3(256), 0, stream>>>(
        sn, wq_t, fnull, parts, snull, 512, 128, 512, 512, 512, 0, 0, 196608);
    k_qred<<<dim3(96), dim3(256), 0, stream>>>(parts, qb);
    k_dots<<<dim3(8, 8, 32), dim3(256), 0, stream>>>(qb, kv, dots);
    k_soft<<<dim3(4, 32), dim3(256), 0, stream>>>(dots, it == 2 ? out + 131328 : fnull);
    k_upd<<<dim3(8, 32), dim3(256), 0, stream>>>(dots, kv, gruA);
    gemm_t<0,false,true><<<dim3(48, 4), dim3(256), 0, stream>>>(
        gruA, wgru, fnull, parts, snull, 2048, 256, 1024, 1024, 2048, 0, 0, 786432);
    k_gruact_sk<<<dim3(768), dim3(256), 0, stream>>>(parts, gbias, slots);
    k_lnb<<<dim3(96), dim3(256), 0, stream>>>(slots, fln, ffnln_g, ffnln_b);
    gemm_t<0,false,true><<<dim3(48, 2), dim3(256), 0, stream>>>(
        fln, w1_t, fnull, parts, snull, 2048, 256, 512, 512, 2048, 0, 0, 786432);
    k_ffn1red<<<dim3(384), dim3(256), 0, stream>>>(parts, ffn_b1, f1);
    gemm_t<0,false,true><<<dim3(12, 8), dim3(256), 0, stream>>>(
        f1, w2_t, fnull, parts, snull, 512, 256, 2048, 2048, 512, 0, 0, 196608);
    k_ffn2red<<<dim3(96), dim3(256), 0, stream>>>(parts, ffn_b2, slots, gruA);
  }

  gemm_t<2,false,false><<<dim3(6), dim3(256), 0, stream>>>(
      gruA + 512, sl1_t, sel_b1, hid, snull, 256, 512, 1024, 512, 256, 0, 0, 0);
  k_decide<<<dim3(32), dim3(64), 0, stream>>>(hid, sel_w2, sel_b2, slots, out);
}

// Round 6
// 551.679 us; speedup vs baseline: 2.9174x; 1.1275x over previous
//
#include <hip/hip_runtime.h>
#include <math.h>

typedef __attribute__((ext_vector_type(8))) short short8;
typedef __attribute__((ext_vector_type(4))) float f32x4;

typedef const __attribute__((address_space(1))) void gv_t;
typedef __attribute__((address_space(3))) void lv_t;

__device__ __forceinline__ float b2f(short u) {
  union { unsigned int i; float f; } c; c.i = ((unsigned int)(unsigned short)u) << 16; return c.f;
}
__device__ __forceinline__ short f2b(float f) {
  union { float f; unsigned int i; } c; c.f = f;
  unsigned int r = c.i + 0x7FFFu + ((c.i >> 16) & 1u);
  return (short)(r >> 16);
}
__device__ __forceinline__ void glds(const short* g, short* l) {
  __builtin_amdgcn_global_load_lds((gv_t*)g, (lv_t*)l, 16, 0, 0);
}

// ---------------- prep kernels ----------------

__global__ __launch_bounds__(256) void k_convA(const float* __restrict__ in, short* __restrict__ out, int n8) {
  int idx = blockIdx.x * 256 + threadIdx.x;
  if (idx >= n8) return;
  const float4* p = (const float4*)(in + (size_t)idx * 8);
  float4 a = p[0], b = p[1];
  short8 r;
  r[0]=f2b(a.x); r[1]=f2b(a.y); r[2]=f2b(a.z); r[3]=f2b(a.w);
  r[4]=f2b(b.x); r[5]=f2b(b.y); r[6]=f2b(b.z); r[7]=f2b(b.w);
  *(short8*)(out + (size_t)idx*8) = r;
}

// mega prep: all weight transposes + GRU combine + slots init

__global__ __launch_bounds__(256) void k_prep(
    const float* __restrict__ w_in, const float* __restrict__ wk, const float* __restrict__ wv,
    const float* __restrict__ wq, const float* __restrict__ wih, const float* __restrict__ whh,
    const float* __restrict__ bih, const float* __restrict__ bhh,
    const float* __restrict__ w1, const float* __restrict__ w2, const float* __restrict__ sl1,
    const float* __restrict__ mu, const float* __restrict__ lsig, const float* __restrict__ noise,
    short* __restrict__ Bt1, short* __restrict__ Btkv, short* __restrict__ wq_t,
    short* __restrict__ wgru, float* __restrict__ gbias,
    short* __restrict__ w1_t, short* __restrict__ w2_t, short* __restrict__ sl1_t,
    float* __restrict__ slots, short* __restrict__ gruA)
{
  int blk = blockIdx.x, t = threadIdx.x;
  if (blk < 2304) {                       // w_in (1152x512) -> Bt1 (512x1152)
    int idx = blk*256 + t;
    int kk = idx / 512, n = idx % 512;
    Bt1[(size_t)n*1152 + kk] = f2b(w_in[idx]);
  } else if (blk < 4352) {                // [wk|wv] -> Btkv (1024x512)
    int idx = (blk-2304)*256 + t;
    int kk = idx >> 10, n = idx & 1023;
    float v = (n < 512) ? wk[kk*512 + n] : wv[kk*512 + (n-512)];
    Btkv[(size_t)n*512 + kk] = f2b(v);
  } else if (blk < 5376) {                // wq (512x512) -> wq_t
    int idx = (blk-4352)*256 + t;
    int kk = idx >> 9, n = idx & 511;
    wq_t[n*512 + kk] = f2b(wq[idx]);
  } else if (blk < 13568) {               // combined GRU weight (2048 x 1024): [r|z|xn|hn]
    int idx = (blk-5376)*256 + t;
    int n = idx >> 10, k = idx & 1023;
    int g = n >> 9, c = n & 511;
    float v;
    if (g == 0)      v = (k < 512) ? wih[k*1536 + c]        : whh[(k-512)*1536 + c];
    else if (g == 1) v = (k < 512) ? wih[k*1536 + 512 + c]  : whh[(k-512)*1536 + 512 + c];
    else if (g == 2) v = (k < 512) ? wih[k*1536 + 1024 + c] : 0.f;
    else             v = (k < 512) ? 0.f                    : whh[(k-512)*1536 + 1024 + c];
    wgru[(size_t)n*1024 + k] = f2b(v);
  } else if (blk < 17664) {               // ffn_w1 (512x2048) -> w1_t (2048x512)
    int idx = (blk-13568)*256 + t;
    int kk = idx >> 11, n = idx & 2047;
    w1_t[(size_t)n*512 + kk] = f2b(w1[idx]);
  } else if (blk < 21760) {               // ffn_w2 (2048x512) -> w2_t (512x2048)
    int idx = (blk-17664)*256 + t;
    int kk = idx >> 9, n = idx & 511;
    w2_t[(size_t)n*2048 + kk] = f2b(w2[idx]);
  } else if (blk < 22272) {               // sel_w1 (512x256) -> sl1_t (256x512)
    int idx = (blk-21760)*256 + t;
    int kk = idx >> 8, n = idx & 255;
    sl1_t[n*512 + kk] = f2b(sl1[idx]);
  } else if (blk < 22280) {               // combined GRU bias (2048)
    int n = (blk-22272)*256 + t;
    int g = n >> 9;
    float v;
    if (g <= 1)      v = bih[n] + bhh[n];
    else if (g == 2) v = bih[n];
    else             v = bhh[1024 + (n - 1536)];
    gbias[n] = v;
  } else {                                // slots init (fp32 + bf16 into gruA 2nd half)
    int idx = (blk-22280)*256 + t;
    int sd = idx % 6144;
    float v = mu[sd] + __expf(lsig[sd]) * noise[idx];
    slots[idx] = v;
    int row = idx >> 9, c = idx & 511;
    gruA[(size_t)row*1024 + 512 + c] = f2b(v);
  }
}

// ---------------- big-GEMM: dbuf + counted-vmcnt pipeline (T3/T4, raw barriers) ----------------
// C = A(MxK) @ Bt(NxK)^T (+bias), bf16 out. 128x128 tile, BK=64, 2 LDS buffers (64KB).
// Steady state: {ds_read all frags(cur); lgkmcnt(0); barrier; stage(t+2 -> cur);
// MFMA x32; vmcnt(8); barrier} -- loads stay in flight a full K-step (never drain to 0).
// T1 bijective XCD swizzle; both-sides LDS XOR swizzle as before.

__global__ __launch_bounds__(256) void gemm_p(
    const short* __restrict__ A, const short* __restrict__ Bt,
    const float* __restrict__ bias, short* __restrict__ Cb,
    int N, int K, int lda, int ldb)
{
  __shared__ short As[2][128*64];
  __shared__ short Bs[2][128*64];
  const int t = threadIdx.x;
  const int lane = t & 63, wave = t >> 6;

  const int nwg = gridDim.x, gridX = N >> 7, orig = blockIdx.x;
  const int q = nwg >> 3, r = nwg & 7, xcd = orig & 7, base = orig >> 3;
  const int wgid = (xcd < r ? xcd*(q+1) : r*(q+1) + (xcd - r)*q) + base;
  const int bx = wgid % gridX, by = wgid / gridX;

  const int rowBase = by * 128, colBase = bx * 128;
  const int wm = (wave >> 1) * 64, wn = (wave & 1) * 64;
  const int fr = lane & 15, kcf = lane >> 4;
  f32x4 acc[4][4] = {};

  int srow[4], scol[4];
  #pragma unroll
  for (int i = 0; i < 4; ++i) {
    int c = i*256 + t;
    srow[i] = c >> 3;
    scol[i] = ((c & 7) ^ (srow[i] & 7)) * 8;
  }

  const int nsteps = K >> 6;
  auto STAGE = [&](int step, int buf) {
    int kb = step * 64;
    #pragma unroll
    for (int i = 0; i < 4; ++i) {
      int c = i*256 + t;
      glds(A + (size_t)(rowBase + srow[i])*lda + kb + scol[i], As[buf] + c*8);
      glds(Bt + (size_t)(colBase + srow[i])*ldb + kb + scol[i], Bs[buf] + c*8);
    }
  };

  STAGE(0, 0);
  if (nsteps > 1) { STAGE(1, 1); asm volatile("s_waitcnt vmcnt(8)" ::: "memory"); }
  else            {              asm volatile("s_waitcnt vmcnt(0)" ::: "memory"); }
  __builtin_amdgcn_sched_barrier(0);
  __builtin_amdgcn_s_barrier();
  __builtin_amdgcn_sched_barrier(0);

  for (int tt = 0; tt < nsteps; ++tt) {
    const int cur = tt & 1;
    short8 af[2][4], bf[2][4];
    #pragma unroll
    for (int ks = 0; ks < 2; ++ks) {
      int kc = ks*4 + kcf;
      #pragma unroll
      for (int m = 0; m < 4; ++m) {
        int rowa = wm + m*16 + fr;
        af[ks][m] = *(const short8*)(As[cur] + rowa*64 + (kc ^ (rowa & 7))*8);
        int rowb = wn + m*16 + fr;
        bf[ks][m] = *(const short8*)(Bs[cur] + rowb*64 + (kc ^ (rowb & 7))*8);
      }
    }
    asm volatile("s_waitcnt lgkmcnt(0)" ::: "memory");
    __builtin_amdgcn_sched_barrier(0);
    __builtin_amdgcn_s_barrier();          // all waves done reading buf[cur]
    __builtin_amdgcn_sched_barrier(0);
    if (tt + 2 < nsteps) STAGE(tt + 2, cur);
    #pragma unroll
    for (int ks = 0; ks < 2; ++ks)
      #pragma unroll
      for (int m = 0; m < 4; ++m)
        #pragma unroll
        for (int n = 0; n < 4; ++n)
          acc[m][n] = __builtin_amdgcn_mfma_f32_16x16x32_bf16(af[ks][m], bf[ks][n], acc[m][n], 0, 0, 0);
    if (tt + 1 < nsteps) {
      if (tt + 2 < nsteps) asm volatile("s_waitcnt vmcnt(8)" ::: "memory");
      else                 asm volatile("s_waitcnt vmcnt(0)" ::: "memory");
      __builtin_amdgcn_sched_barrier(0);
      __builtin_amdgcn_s_barrier();        // buf[cur^1] ready for next iter
      __builtin_amdgcn_sched_barrier(0);
    }
  }

  const int cr = (lane >> 4) * 4, cc2 = lane & 15;
  #pragma unroll
  for (int m = 0; m < 4; ++m)
    #pragma unroll
    for (int n = 0; n < 4; ++n) {
      int col = colBase + wn + n*16 + cc2;
      float bv = bias ? bias[col] : 0.f;
      #pragma unroll
      for (int j = 0; j < 4; ++j) {
        int row = rowBase + wm + m*16 + cr + j;
        Cb[(size_t)row*N + col] = f2b(acc[m][n][j] + bv);
      }
    }
}

// ---------------- small-GEMM (round-5 proven structure, split-K capable) ----------------

template<int ACT, bool OUTBF, bool SPLITK>
__global__ __launch_bounds__(256) void gemm_t(
    const short* __restrict__ A, const short* __restrict__ Bt,
    const float* __restrict__ bias,
    float* __restrict__ Cf, short* __restrict__ Cb,
    int N, int Kp, int lda, int ldb, int ldf, int ldcb, int cboff, int skstride)
{
  __shared__ short As[128*64];
  __shared__ short Bs[128*64];
  const int t = threadIdx.x;
  const int lane = t & 63, wave = t >> 6;

  const int nwg = gridDim.x, gridX = N >> 7, orig = blockIdx.x;
  const int q = nwg >> 3, r = nwg & 7, xcd = orig & 7, base = orig >> 3;
  const int wgid = (xcd < r ? xcd*(q+1) : r*(q+1) + (xcd - r)*q) + base;
  const int bx = wgid % gridX, by = wgid / gridX;

  const int rowBase = by * 128, colBase = bx * 128;
  const size_t koff = (size_t)blockIdx.y * Kp;
  const int wm = (wave >> 1) * 64, wn = (wave & 1) * 64;
  const int fr = lane & 15, kcf = lane >> 4;
  f32x4 acc[4][4] = {};

  int srow[4], scol[4];
  #pragma unroll
  for (int i = 0; i < 4; ++i) {
    int c = i*256 + t;
    srow[i] = c >> 3;
    scol[i] = ((c & 7) ^ (srow[i] & 7)) * 8;
  }

  for (int kb = 0; kb < Kp; kb += 64) {
    __syncthreads();
    #pragma unroll
    for (int i = 0; i < 4; ++i) {
      int c = i*256 + t;
      glds(A + (size_t)(rowBase + srow[i])*lda + koff + kb + scol[i], As + c*8);
      glds(Bt + (size_t)(colBase + srow[i])*ldb + koff + kb + scol[i], Bs + c*8);
    }
    __syncthreads();
    #pragma unroll
    for (int ks = 0; ks < 2; ++ks) {
      short8 af[4], bf[4];
      #pragma unroll
      for (int m = 0; m < 4; ++m) {
        int row = wm + m*16 + fr;
        int kc = ks*4 + kcf;
        af[m] = *(const short8*)(As + row*64 + (kc ^ (row & 7))*8);
      }
      #pragma unroll
      for (int n = 0; n < 4; ++n) {
        int row = wn + n*16 + fr;
        int kc = ks*4 + kcf;
        bf[n] = *(const short8*)(Bs + row*64 + (kc ^ (row & 7))*8);
      }
      #pragma unroll
      for (int m = 0; m < 4; ++m)
        #pragma unroll
        for (int n = 0; n < 4; ++n)
          acc[m][n] = __builtin_amdgcn_mfma_f32_16x16x32_bf16(af[m], bf[n], acc[m][n], 0, 0, 0);
    }
  }

  const int cr = (lane >> 4) * 4, cc2 = lane & 15;
  if (SPLITK) {
    float* dst = Cf + (size_t)blockIdx.y * skstride;
    #pragma unroll
    for (int m = 0; m < 4; ++m)
      #pragma unroll
      for (int n = 0; n < 4; ++n) {
        int col = colBase + wn + n*16 + cc2;
        #pragma unroll
        for (int j = 0; j < 4; ++j) {
          int row = rowBase + wm + m*16 + cr + j;
          dst[(size_t)row * ldf + col] = acc[m][n][j];
        }
      }
  } else {
    #pragma unroll
    for (int m = 0; m < 4; ++m)
      #pragma unroll
      for (int n = 0; n < 4; ++n) {
        int col = colBase + wn + n*16 + cc2;
        float bv = bias ? bias[col] : 0.f;
        #pragma unroll
        for (int j = 0; j < 4; ++j) {
          int row = rowBase + wm + m*16 + cr + j;
          float v = acc[m][n][j] + bv;
          if (ACT == 1) v = 0.5f*v*(1.f + erff(v*0.70710678118f));
          else if (ACT == 2) v = fmaxf(v, 0.f);
          if (OUTBF) Cb[(size_t)row*ldcb + cboff + col] = f2b(v);
          else Cf[(size_t)row*ldf + col] = v;
        }
      }
  }
}

// ---------------- split-K reduce kernels ----------------

__global__ __launch_bounds__(256) void k_gruact_sk(const float* __restrict__ p, const float* __restrict__ gbias,
                                                   float* __restrict__ slots)
{
  int idx = blockIdx.x*256 + threadIdx.x; // 196608
  int row = idx >> 9, c = idx & 511;
  const float* base = p + (size_t)row*2048 + c;
  float g0=gbias[c], g1=gbias[512+c], g2=gbias[1024+c], g3=gbias[1536+c];
  #pragma unroll
  for (int s = 0; s < 4; ++s) {
    const float* qq = base + (size_t)s*786432;
    g0 += qq[0]; g1 += qq[512]; g2 += qq[1024]; g3 += qq[1536];
  }
  float r = 1.f/(1.f+__expf(-g0));
  float z = 1.f/(1.f+__expf(-g1));
  float n = tanhf(g2 + r*g3);
  slots[idx] = (1.f-z)*n + z*slots[idx];
}

__global__ __launch_bounds__(256) void k_ffn1red(const float* __restrict__ p, const float* __restrict__ b1,
                                                 short* __restrict__ f1) {
  int i = blockIdx.x*256 + threadIdx.x; // 98304
  int col = (i*8) & 2047;
  float v[8], w[8];
  *(float4*)v = *(const float4*)(p + (size_t)i*8);
  *(float4*)(v+4) = *(const float4*)(p + (size_t)i*8 + 4);
  const float* p2 = p + 786432;
  *(float4*)w = *(const float4*)(p2 + (size_t)i*8);
  *(float4*)(w+4) = *(const float4*)(p2 + (size_t)i*8 + 4);
  short8 o;
  #pragma unroll
  for (int e = 0; e < 8; ++e) {
    float x = v[e] + w[e] + b1[col + e];
    x = 0.5f*x*(1.f + erff(x*0.70710678118f));
    o[e] = f2b(x);
  }
  *(short8*)(f1 + (size_t)i*8) = o;
}

__global__ __launch_bounds__(256) void k_ffn2red(const float* __restrict__ p, const float* __restrict__ b2,
                                                 float* __restrict__ slots, short* __restrict__ gruA) {
  int i = blockIdx.x*256 + threadIdx.x; // 24576
  int base = i*8;
  int row = base >> 9, c = base & 511;
  float v[8] = {0.f,0.f,0.f,0.f,0.f,0.f,0.f,0.f};
  #pragma unroll
  for (int s = 0; s < 8; ++s) {
    const float* qq = p + (size_t)s*196608 + base;
    float4 a = *(const float4*)qq, b = *(const float4*)(qq+4);
    v[0]+=a.x; v[1]+=a.y; v[2]+=a.z; v[3]+=a.w;
    v[4]+=b.x; v[5]+=b.y; v[6]+=b.z; v[7]+=b.w;
  }
  float sl[8];
  *(float4*)sl = *(const float4*)(slots + base);
  *(float4*)(sl+4) = *(const float4*)(slots + base + 4);
  short8 o;
  #pragma unroll
  for (int e = 0; e < 8; ++e) {
    float ns = sl[e] + v[e] + b2[c+e];
    sl[e] = ns;
    o[e] = f2b(ns);
  }
  *(float4*)(slots + base) = *(float4*)sl;
  *(float4*)(slots + base + 4) = *(float4*)(sl+4);
  *(short8*)(gruA + (size_t)row*1024 + 512 + c) = o;
}

// ---------------- double layernorm: inp = LN2(LN1(y)), bf16 in/out, wave per row ----------------

__global__ __launch_bounds__(256) void k_ln2(const short* __restrict__ y, short* __restrict__ inp,
    const float* __restrict__ g1, const float* __restrict__ b1,
    const float* __restrict__ g2, const float* __restrict__ b2)
{
  int t = threadIdx.x, lane = t & 63;
  int row = blockIdx.x * 4 + (t >> 6);
  const short8 raw = *(const short8*)(y + (size_t)row*512 + lane*8);
  float x[8];
  #pragma unroll
  for (int e = 0; e < 8; ++e) x[e] = b2f(raw[e]);
  float s = 0.f, ss = 0.f;
  #pragma unroll
  for (int e = 0; e < 8; ++e) { s += x[e]; ss += x[e]*x[e]; }
  #pragma unroll
  for (int m = 1; m < 64; m <<= 1) { s += __shfl_xor(s, m, 64); ss += __shfl_xor(ss, m, 64); }
  float mean = s * (1.f/512.f);
  float rs = rsqrtf(ss*(1.f/512.f) - mean*mean + 1e-5f);
  int c = lane * 8;
  #pragma unroll
  for (int e = 0; e < 8; ++e) x[e] = (x[e]-mean)*rs*g1[c+e] + b1[c+e];
  s = 0.f; ss = 0.f;
  #pragma unroll
  for (int e = 0; e < 8; ++e) { s += x[e]; ss += x[e]*x[e]; }
  #pragma unroll
  for (int m = 1; m < 64; m <<= 1) { s += __shfl_xor(s, m, 64); ss += __shfl_xor(ss, m, 64); }
  float mean2 = s * (1.f/512.f);
  float rs2 = rsqrtf(ss*(1.f/512.f) - mean2*mean2 + 1e-5f);
  short8 o;
  #pragma unroll
  for (int e = 0; e < 8; ++e) o[e] = f2b((x[e]-mean2)*rs2*g2[c+e] + b2[c+e]);
  *(short8*)(inp + (size_t)row*512 + lane*8) = o;
}

// ---------------- layernorm fp32 -> bf16, wave per row (512 cols) ----------------

__global__ __launch_bounds__(256) void k_lnb(const float* __restrict__ x, short* __restrict__ out,
    const float* __restrict__ g, const float* __restrict__ b)
{
  int t = threadIdx.x, lane = t & 63;
  int row = blockIdx.x * 4 + (t >> 6);
  const float* src = x + (size_t)row*512 + lane*8;
  float v[8];
  *(float4*)v = *(const float4*)src;
  *(float4*)(v+4) = *(const float4*)(src+4);
  float s = 0.f, ss = 0.f;
  #pragma unroll
  for (int e = 0; e < 8; ++e) { s += v[e]; ss += v[e]*v[e]; }
  #pragma unroll
  for (int m = 1; m < 64; m <<= 1) { s += __shfl_xor(s, m, 64); ss += __shfl_xor(ss, m, 64); }
  float mean = s * (1.f/512.f);
  float rs = rsqrtf(ss*(1.f/512.f) - mean*mean + 1e-5f);
  int c = lane * 8;
  short8 o;
  #pragma unroll
  for (int e = 0; e < 8; ++e) o[e] = f2b((v[e]-mean)*rs*g[c+e] + b[c+e]);
  *(short8*)(out + (size_t)row*512 + c) = o;
}

// ---------------- fused attention: q-sum + dots + softmax + pv partials ----------------
// grid (jt=8, b=32), 256 thr, ~106KB LDS (1 block/CU).
// Softmax axis is the 96 (s,h) pairs per (b,j) -- block-local. Only den (sum over j)
// is global: emit pv/den partials per jt, reduced by k_pvred.

__global__ __launch_bounds__(256) void k_attn(
    const float* __restrict__ qparts, const short* __restrict__ kv,
    float* __restrict__ pvp, float* __restrict__ denp, float* __restrict__ aout)
{
  __shared__ float qs[12][512];
  __shared__ float ksh[128][65];
  __shared__ float dots[96][132];
  const int t = threadIdx.x;
  const int jt = blockIdx.x, b = blockIdx.y;

  // stage q = sum of 4 wq split-K partials
  for (int i = t; i < 6144; i += 256) {
    int s = i >> 9, d = i & 511;
    size_t o = (size_t)(b*12+s)*512 + d;
    qs[s][d] = qparts[o] + qparts[196608 + o] + qparts[393216 + o] + qparts[589824 + o];
  }

  const int jj = t & 127, sg = t >> 7;
  for (int h = 0; h < 8; ++h) {
    __syncthreads();
    #pragma unroll
    for (int i = 0; i < 4; ++i) {
      int c = i*256 + t;
      int j2 = c >> 3, seg = (c & 7) * 8;
      short8 raw = *(const short8*)(kv + ((size_t)(b*1024 + jt*128 + j2))*1024 + h*64 + seg);
      #pragma unroll
      for (int e = 0; e < 8; ++e) ksh[j2][seg+e] = b2f(raw[e]);
    }
    __syncthreads();
    float d6[6] = {};
    for (int d = 0; d < 64; ++d) {
      float kvv = ksh[jj][d];
      #pragma unroll
      for (int i = 0; i < 6; ++i) d6[i] += qs[sg*6+i][h*64+d] * kvv;
    }
    #pragma unroll
    for (int i = 0; i < 6; ++i) dots[(sg*6+i)*8 + h][jj] = d6[i] * 0.125f;
  }
  __syncthreads();

  // softmax over 96 per j: 2 threads per j (halves of 48), shfl-combine
  {
    int j = t >> 1, half = (t & 1) * 48;
    float mx = -1e30f;
    #pragma unroll
    for (int i = 0; i < 48; ++i) mx = fmaxf(mx, dots[half+i][j]);
    mx = fmaxf(mx, __shfl_xor(mx, 1, 64));
    float ex[48];
    float sum = 0.f;
    #pragma unroll
    for (int i = 0; i < 48; ++i) { ex[i] = __expf(dots[half+i][j] - mx); sum += ex[i]; }
    sum += __shfl_xor(sum, 1, 64);
    float inv = 1.f / sum;
    float as_[6] = {0,0,0,0,0,0};
    #pragma unroll
    for (int i = 0; i < 48; ++i) {
      float a = ex[i] * inv;
      dots[half+i][j] = a;
      as_[i >> 3] += a;
    }
    if (aout) {
      int sbase = (t & 1) * 6;
      #pragma unroll
      for (int q2 = 0; q2 < 6; ++q2) {
        int s = sbase + q2;
        if (s < 8) aout[((size_t)(b*8+s))*1024 + jt*128 + j] = as_[q2] * 0.125f;
      }
    }
  }

  // pv partials per h + den partials
  const int d = t & 63, sq = t >> 6;
  for (int h = 0; h < 8; ++h) {
    __syncthreads();
    #pragma unroll
    for (int i = 0; i < 4; ++i) {
      int c = i*256 + t;
      int j2 = c >> 3, seg = (c & 7) * 8;
      short8 raw = *(const short8*)(kv + ((size_t)(b*1024 + jt*128 + j2))*1024 + 512 + h*64 + seg);
      #pragma unroll
      for (int e = 0; e < 8; ++e) ksh[j2][seg+e] = b2f(raw[e]);
    }
    __syncthreads();
    float a3[3] = {0.f, 0.f, 0.f};
    for (int j2 = 0; j2 < 128; ++j2) {
      float vv = ksh[j2][d];
      #pragma unroll
      for (int i = 0; i < 3; ++i) a3[i] += dots[(sq + 4*i)*8 + h][j2] * vv;
    }
    #pragma unroll
    for (int i = 0; i < 3; ++i)
      pvp[((size_t)(jt*32+b))*6144 + (sq + 4*i)*512 + h*64 + d] = a3[i];
    if (t < 12) {
      float ls = 0.f;
      for (int j2 = 0; j2 < 128; ++j2) ls += dots[t*8 + h][j2];
      denp[((size_t)(jt*32+b))*96 + t*8 + h] = ls;
    }
  }
}

// pv reduce: sum 8 jt-partials, divide by global den, write gruA bf16 (upd half)

__global__ __launch_bounds__(256) void k_pvred(const float* __restrict__ pvp, const float* __restrict__ denp,
                                               short* __restrict__ gruA)
{
  __shared__ float den[96];
  int t = threadIdx.x, b = blockIdx.x;
  if (t < 96) {
    float s = 0.f;
    #pragma unroll
    for (int jt2 = 0; jt2 < 8; ++jt2) s += denp[((size_t)(jt2*32+b))*96 + t];
    den[t] = s + 1e-8f;
  }
  __syncthreads();
  for (int i = t; i < 6144; i += 256) {
    int s = i >> 9, rem = i & 511, h = rem >> 6;
    float acc = 0.f;
    #pragma unroll
    for (int jt2 = 0; jt2 < 8; ++jt2) acc += pvp[((size_t)(jt2*32+b))*6144 + i];
    gruA[((size_t)(b*12+s))*1024 + rem] = f2b(acc / den[s*8 + h]);
  }
}

// ---------------- selector head: logits, decision logic, obj write ----------------

__global__ __launch_bounds__(64) void k_decide(const float* __restrict__ hid, const float* __restrict__ w2,
    const float* __restrict__ b2, const float* __restrict__ slots, float* __restrict__ out)
{
  __shared__ float lg[16];
  __shared__ float dec[8];
  int b = blockIdx.x, t = threadIdx.x;
  if (t < 16) {
    int s = t >> 1, cl = t & 1;
    const float* hr = hid + (size_t)(b*12+s)*256;
    float a = b2[cl];
    for (int k = 0; k < 256; ++k) a += hr[k] * w2[k*2+cl];
    lg[t] = a;
  }
  __syncthreads();
  if (t == 0) {
    float d0[8]; float tot = 0.f;
    #pragma unroll
    for (int s = 0; s < 8; ++s) { d0[s] = (lg[2*s+1] > lg[2*s]) ? 1.f : 0.f; tot += d0[s]; }
    float needed = fmaxf(0.f, 2.f - tot);
    float cum = 0.f;
    #pragma unroll
    for (int s = 0; s < 8; ++s) {
      cum += 1.f - d0[s];
      float add = (d0[s] == 0.f && cum <= needed) ? 1.f : 0.f;
      float dd = d0[s] + add;
      dec[s] = dd;
      out[131072 + b*8 + s] = dd;
    }
  }
  __syncthreads();
  for (int i = 0; i < 64; ++i) {
    int idx = i*64 + t;
    int s = idx >> 9, c = idx & 511;
    out[(size_t)(b*8+s)*512 + c] = slots[(size_t)(b*12+s)*512 + c] * dec[s];
  }
}

// ---------------- host ----------------

extern "C" void kernel_launch(void* const* d_in, const int* in_sizes, int n_in,
                              void* d_out, int out_size, void* d_ws, size_t ws_size,
                              hipStream_t stream) {
  const float* features = (const float*)d_in[0];
  const float* noise    = (const float*)d_in[1];
  const float* w_in     = (const float*)d_in[2];
  const float* b_in     = (const float*)d_in[3];
  const float* ln1_g    = (const float*)d_in[4];
  const float* ln1_b    = (const float*)d_in[5];
  const float* slot_mu  = (const float*)d_in[6];
  const float* slot_ls  = (const float*)d_in[7];
  const float* wq       = (const float*)d_in[8];
  const float* wk       = (const float*)d_in[9];
  const float* wv       = (const float*)d_in[10];
  const float* gru_wih  = (const float*)d_in[11];
  const float* gru_whh  = (const float*)d_in[12];
  const float* gru_bih  = (const float*)d_in[13];
  const float* gru_bhh  = (const float*)d_in[14];
  const float* nslots_g = (const float*)d_in[15];
  const float* nslots_b = (const float*)d_in[16];
  const float* ninput_g = (const float*)d_in[17];
  const float* ninput_b = (const float*)d_in[18];
  const float* ffnln_g  = (const float*)d_in[19];
  const float* ffnln_b  = (const float*)d_in[20];
  const float* ffn_w1   = (const float*)d_in[21];
  const float* ffn_b1   = (const float*)d_in[22];
  const float* ffn_w2   = (const float*)d_in[23];
  const float* ffn_b2   = (const float*)d_in[24];
  const float* sel_w1   = (const float*)d_in[25];
  const float* sel_b1   = (const float*)d_in[26];
  const float* sel_w2   = (const float*)d_in[27];
  const float* sel_b2   = (const float*)d_in[28];
  float* out = (float*)d_out;
  float* fnull = (float*)nullptr;
  short* snull = (short*)nullptr;

  char* w = (char*)d_ws;
  size_t off = 0;
  auto alloc = [&](size_t n) { char* p = w + off; off = (off + n + 255) & ~255ULL; return p; };
  short* Abf   = (short*)alloc(75497472);   // features bf16; reused as kv
  short* kv    = Abf;
  short* ybf   = (short*)alloc(33554432);   // gemm1 out bf16
  short* inp   = (short*)alloc(33554432);   // LN'd input bf16
  short* Bt1   = (short*)alloc(1179648);
  short* Btkv  = (short*)alloc(1048576);
  short* wq_t  = (short*)alloc(524288);
  short* wgru  = (short*)alloc(4194304);
  float* gbias = (float*)alloc(8192);
  short* w1_t  = (short*)alloc(2097152);
  short* w2_t  = (short*)alloc(2097152);
  short* sl1_t = (short*)alloc(262144);
  float* slots = (float*)alloc(786432);
  short* gruA  = (short*)alloc(786432);
  short* sn    = (short*)alloc(393216);
  float* parts = (float*)alloc(12582912);   // split-K partials
  float* pvp   = (float*)alloc(6291456);    // attention pv partials [8jt][32b][6144]
  float* denp  = (float*)alloc(98304);      // den partials [8jt][32b][96]
  short* fln   = (short*)alloc(393216);
  short* f1    = (short*)alloc(1572864);
  float* hid   = (float*)alloc(393216);
  (void)ws_size; (void)in_sizes; (void)n_in; (void)out_size;

  k_convA<<<dim3(18432), dim3(256), 0, stream>>>(features, Abf, 4718592);
  k_prep<<<dim3(23048), dim3(256), 0, stream>>>(
      w_in, wk, wv, wq, gru_wih, gru_whh, gru_bih, gru_bhh,
      ffn_w1, ffn_w2, sel_w1, slot_mu, slot_ls, noise,
      Bt1, Btkv, wq_t, wgru, gbias, w1_t, w2_t, sl1_t, slots, gruA);

  // phase A
  gemm_p<<<dim3(1024), dim3(256), 0, stream>>>(Abf, Bt1, b_in, ybf, 512, 1152, 1152, 1152);
  k_ln2<<<dim3(8192), dim3(256), 0, stream>>>(ybf, inp, ln1_g, ln1_b, ninput_g, ninput_b);
  gemm_p<<<dim3(2048), dim3(256), 0, stream>>>(inp, Btkv, fnull, kv, 1024, 512, 512, 512);

  for (int it = 0; it < 3; ++it) {
    k_lnb<<<dim3(96), dim3(256), 0, stream>>>(slots, sn, nslots_g, nslots_b);
    gemm_t<0,false,true><<<dim3(12, 4), dim3(256), 0, stream>>>(
        sn, wq_t, fnull, parts, snull, 512, 128, 512, 512, 512, 0, 0, 196608);
    k_attn<<<dim3(8, 32), dim3(256), 0, stream>>>(parts, kv, pvp, denp,
        it == 2 ? out + 131328 : fnull);
    k_pvred<<<dim3(32), dim3(256), 0, stream>>>(pvp, denp, gruA);
    gemm_t<0,false,true><<<dim3(48, 4), dim3(256), 0, stream>>>(
        gruA, wgru, fnull, parts, snull, 2048, 256, 1024, 1024, 2048, 0, 0, 786432);
    k_gruact_sk<<<dim3(768), dim3(256), 0, stream>>>(parts, gbias, slots);
    k_lnb<<<dim3(96), dim3(256), 0, stream>>>(slots, fln, ffnln_g, ffnln_b);
    gemm_t<0,false,true><<<dim3(48, 2), dim3(256), 0, stream>>>(
        fln, w1_t, fnull, parts, snull, 2048, 256, 512, 512, 2048, 0, 0, 786432);
    k_ffn1red<<<dim3(384), dim3(256), 0, stream>>>(parts, ffn_b1, f1);
    gemm_t<0,false,true><<<dim3(12, 8), dim3(256), 0, stream>>>(
        f1, w2_t, fnull, parts, snull, 512, 256, 2048, 2048, 512, 0, 0, 196608);
    k_ffn2red<<<dim3(96), dim3(256), 0, stream>>>(parts, ffn_b2, slots, gruA);
  }

  gemm_t<2,false,false><<<dim3(6), dim3(256), 0, stream>>>(
      gruA + 512, sl1_t, sel_b1, hid, snull, 256, 512, 1024, 512, 256, 0, 0, 0);
  k_decide<<<dim3(32), dim3(64), 0, stream>>>(hid, sel_w2, sel_b2, slots, out);
}